// Round 1
// baseline (486.980 us; speedup 1.0000x reference)
//
#include <hip/hip_runtime.h>

#define N_NODES 50000
#define NFEAT 128
#define NEDGE 800000
#define NGRAPH 512
#define NCE 64
#define EPS 1e-5f

// ---------- bf16 helpers (manual, bit-exact RNE) ----------
static __device__ __forceinline__ unsigned short f2bf(float f) {
    unsigned int u = __float_as_uint(f);
    unsigned int r = u + 0x7fffu + ((u >> 16) & 1u);
    return (unsigned short)(r >> 16);
}
static __device__ __forceinline__ float bf_lo(unsigned int packed) {
    return __uint_as_float(packed << 16);
}
static __device__ __forceinline__ float bf_hi(unsigned int packed) {
    return __uint_as_float(packed & 0xffff0000u);
}

// ---------- degree histogram ----------
__global__ void hist_kernel(const int* __restrict__ ei, int* __restrict__ degint, int E) {
    int e = blockIdx.x * blockDim.x + threadIdx.x;
    if (e < E) atomicAdd(&degint[ei[E + e]], 1);   // dst = ei[E+e]
}

// ---------- dinv = rsqrt(indeg + 1 self loop) ----------
__global__ void dinv_kernel(const int* __restrict__ degint, float* __restrict__ dinv, int n) {
    int v = blockIdx.x * blockDim.x + threadIdx.x;
    if (v < n) dinv[v] = rsqrtf((float)degint[v] + 1.0f);
}

// ---------- 3-phase exclusive scan over degint -> rowptr ----------
__global__ void scanA_kernel(const int* __restrict__ cnt, int* __restrict__ rowptr,
                             int* __restrict__ bsum, int n) {
    __shared__ int s[256];
    int tid = threadIdx.x;
    int i = blockIdx.x * 256 + tid;
    int v = (i < n) ? cnt[i] : 0;
    s[tid] = v; __syncthreads();
    for (int off = 1; off < 256; off <<= 1) {
        int t = (tid >= off) ? s[tid - off] : 0;
        __syncthreads();
        s[tid] += t;
        __syncthreads();
    }
    if (i < n) rowptr[i] = s[tid] - v;        // local exclusive
    if (tid == 255) bsum[blockIdx.x] = s[255];
}
__global__ void scanB_kernel(const int* __restrict__ bsum, int* __restrict__ boff,
                             int* __restrict__ rowptr, int nb, int n) {
    __shared__ int s[256];
    int tid = threadIdx.x;
    int v = (tid < nb) ? bsum[tid] : 0;
    s[tid] = v; __syncthreads();
    for (int off = 1; off < 256; off <<= 1) {
        int t = (tid >= off) ? s[tid - off] : 0;
        __syncthreads();
        s[tid] += t;
        __syncthreads();
    }
    if (tid < nb) boff[tid] = s[tid] - v;     // exclusive
    if (tid == nb - 1) rowptr[n] = s[tid];    // total = E
}
__global__ void scanC_kernel(int* __restrict__ rowptr, int* __restrict__ cursor,
                             const int* __restrict__ boff, int n) {
    int i = blockIdx.x * 256 + threadIdx.x;
    if (i < n) {
        int r = rowptr[i] + boff[blockIdx.x];
        rowptr[i] = r;
        cursor[i] = r;
    }
}

// ---------- scatter edges into CSR buckets ----------
__global__ void scatter_kernel(const int* __restrict__ ei, int* __restrict__ cursor,
                               int* __restrict__ colidx, int E) {
    int e = blockIdx.x * blockDim.x + threadIdx.x;
    if (e < E) {
        int sv = ei[e];
        int dv = ei[E + e];
        int pos = atomicAdd(&cursor[dv], 1);
        colidx[pos] = sv;
    }
}

// ---------- GEMM: HS[r][c] = bf16( (X @ W)[r][c] * dinv[r] ) ----------
// block 256 threads, tile 64 rows x 128 cols, per-thread 8x4, K chunked by 32
__global__ __launch_bounds__(256) void gemm_scale_kernel(
    const float* __restrict__ X, const float* __restrict__ W,
    const float* __restrict__ dinv, unsigned short* __restrict__ HS, int nrows)
{
    __shared__ __align__(16) float xsT[32 * 72];   // [k][row], stride 72 (16B-aligned rows, 2-way-free banks)
    __shared__ __align__(16) float ws[32 * 128];   // [k][col]
    const int tid = threadIdx.x;
    const int row0 = blockIdx.x * 64;
    const int tc = tid & 31;    // col group: cols tc*4 .. tc*4+3
    const int tr = tid >> 5;    // row group: rows tr*8 .. tr*8+7
    float acc[8][4];
#pragma unroll
    for (int i = 0; i < 8; ++i)
#pragma unroll
        for (int j = 0; j < 4; ++j) acc[i][j] = 0.f;

    for (int kb = 0; kb < 128; kb += 32) {
        __syncthreads();
        // stage X tile (64 rows x 32 k) transposed: 512 float4s, 2 per thread
#pragma unroll
        for (int i = 0; i < 2; ++i) {
            int f4 = tid + i * 256;
            int r = f4 >> 3;          // 0..63
            int kq = f4 & 7;          // k/4
            int rr = row0 + r;
            if (rr >= nrows) rr = nrows - 1;
            const float4 v = *reinterpret_cast<const float4*>(&X[rr * 128 + kb + kq * 4]);
            xsT[(kq * 4 + 0) * 72 + r] = v.x;
            xsT[(kq * 4 + 1) * 72 + r] = v.y;
            xsT[(kq * 4 + 2) * 72 + r] = v.z;
            xsT[(kq * 4 + 3) * 72 + r] = v.w;
        }
        // stage W tile (32 k x 128 cols): 1024 float4s, 4 per thread
#pragma unroll
        for (int i = 0; i < 4; ++i) {
            int f4 = tid + i * 256;
            int k = f4 >> 5, c4 = f4 & 31;
            *reinterpret_cast<float4*>(&ws[k * 128 + c4 * 4]) =
                *reinterpret_cast<const float4*>(&W[(kb + k) * 128 + c4 * 4]);
        }
        __syncthreads();
#pragma unroll
        for (int k = 0; k < 32; ++k) {
            const float4 a0 = *reinterpret_cast<const float4*>(&xsT[k * 72 + tr * 8]);
            const float4 a1 = *reinterpret_cast<const float4*>(&xsT[k * 72 + tr * 8 + 4]);
            const float4 bb = *reinterpret_cast<const float4*>(&ws[k * 128 + tc * 4]);
            float av[8] = {a0.x, a0.y, a0.z, a0.w, a1.x, a1.y, a1.z, a1.w};
            float bv[4] = {bb.x, bb.y, bb.z, bb.w};
#pragma unroll
            for (int i = 0; i < 8; ++i)
#pragma unroll
                for (int j = 0; j < 4; ++j)
                    acc[i][j] = fmaf(av[i], bv[j], acc[i][j]);
        }
    }
    // epilogue: scale by dinv[row], cast bf16, store 4 cols (8B) per row
#pragma unroll
    for (int i = 0; i < 8; ++i) {
        int r = row0 + tr * 8 + i;
        if (r < nrows) {
            float s = dinv[r];
            ushort4 o;
            o.x = f2bf(acc[i][0] * s);
            o.y = f2bf(acc[i][1] * s);
            o.z = f2bf(acc[i][2] * s);
            o.w = f2bf(acc[i][3] * s);
            *reinterpret_cast<ushort4*>(&HS[r * 128 + tc * 4]) = o;
        }
    }
}

// ---------- aggregation: one wave per node ----------
// OUT[v] = relu( dinv[v] * (sum_{u in in(v)} HS[u] + HS[v]) + bias )
__global__ __launch_bounds__(256) void aggregate_kernel(
    const unsigned int* __restrict__ H,       // bf16x2 packed, [N][64]
    const int* __restrict__ rowptr, const int* __restrict__ colidx,
    const float* __restrict__ dinv, const float* __restrict__ bias,
    float* __restrict__ OUT, int n)
{
    int wid = (blockIdx.x * blockDim.x + threadIdx.x) >> 6;
    int lane = threadIdx.x & 63;
    if (wid >= n) return;
    unsigned int self = H[wid * 64 + lane];
    float a0 = bf_lo(self);
    float a1 = bf_hi(self);
    int beg = rowptr[wid], end = rowptr[wid + 1];
    for (int i = beg; i < end; ++i) {
        int u = colidx[i];
        unsigned int t = H[u * 64 + lane];
        a0 += bf_lo(t);
        a1 += bf_hi(t);
    }
    float s = dinv[wid];
    float b0 = bias[lane * 2 + 0];
    float b1 = bias[lane * 2 + 1];
    float2 o;
    o.x = fmaxf(fmaf(a0, s, b0), 0.f);
    o.y = fmaxf(fmaf(a1, s, b1), 0.f);
    *reinterpret_cast<float2*>(&OUT[wid * 128 + lane * 2]) = o;
}

// ---------- global add pool exploiting sorted batch ----------
__global__ __launch_bounds__(128) void pool_kernel(
    const float* __restrict__ H2, const int* __restrict__ batch,
    float* __restrict__ g, int n)
{
    int j = threadIdx.x;
    int n0 = blockIdx.x * 128;
    int n1 = min(n0 + 128, n);
    if (n0 >= n) return;
    float acc = 0.f;
    int cur = batch[n0];
    for (int v = n0; v < n1; ++v) {
        int b = batch[v];
        if (b != cur) {
            atomicAdd(&g[cur * 128 + j], acc);
            acc = 0.f;
            cur = b;
        }
        acc += H2[v * 128 + j];
    }
    atomicAdd(&g[cur * 128 + j], acc);
}

// ---------- fused tail: concat -> fc+LN+relu -> fc+relu -> LN -> fc ----------
static __device__ __forceinline__ float block_ln(float x, float w, float b,
                                                 float* red, int j, bool relu_after) {
    red[j] = x; __syncthreads();
    for (int off = 64; off > 0; off >>= 1) {
        if (j < off) red[j] += red[j + off];
        __syncthreads();
    }
    float mu = red[0] * (1.f / 128.f);
    __syncthreads();
    float d = x - mu;
    red[j] = d * d; __syncthreads();
    for (int off = 64; off > 0; off >>= 1) {
        if (j < off) red[j] += red[j + off];
        __syncthreads();
    }
    float var = red[0] * (1.f / 128.f);
    __syncthreads();
    float y = d * rsqrtf(var + EPS) * w + b;
    return relu_after ? fmaxf(y, 0.f) : y;
}

__global__ __launch_bounds__(128) void tail_kernel(
    const float* __restrict__ g, const int* __restrict__ cell,
    const float* __restrict__ emb,
    const float* __restrict__ Wc, const float* __restrict__ bc,
    const float* __restrict__ lncw, const float* __restrict__ lncb,
    const float* __restrict__ Wf1, const float* __restrict__ bf1,
    const float* __restrict__ ln1w, const float* __restrict__ ln1b,
    const float* __restrict__ Wf2, const float* __restrict__ bf2,
    float* __restrict__ out)
{
    __shared__ float comb[192];
    __shared__ float red[128];
    __shared__ float vec[128];
    int gi = blockIdx.x, j = threadIdx.x;
    comb[j] = g[gi * 128 + j];
    if (j < 64) comb[128 + j] = emb[cell[gi] * 64 + j];
    __syncthreads();
    // fc_comb + LN + relu
    float acc = bc[j];
#pragma unroll 4
    for (int k = 0; k < 192; ++k) acc = fmaf(comb[k], Wc[k * 128 + j], acc);
    acc = block_ln(acc, lncw[j], lncb[j], red, j, true);
    vec[j] = acc; __syncthreads();
    // fc1 + relu
    float acc2 = bf1[j];
#pragma unroll 4
    for (int k = 0; k < 128; ++k) acc2 = fmaf(vec[k], Wf1[k * 128 + j], acc2);
    acc2 = fmaxf(acc2, 0.f);
    // LN (no relu)
    acc2 = block_ln(acc2, ln1w[j], ln1b[j], red, j, false);
    __syncthreads();
    vec[j] = acc2; __syncthreads();
    // fc2
    float acc3 = bf2[j];
#pragma unroll 4
    for (int k = 0; k < 128; ++k) acc3 = fmaf(vec[k], Wf2[k * 128 + j], acc3);
    out[gi * 128 + j] = acc3;
}

// ---------- host launch ----------
extern "C" void kernel_launch(void* const* d_in, const int* in_sizes, int n_in,
                              void* d_out, int out_size, void* d_ws, size_t ws_size,
                              hipStream_t stream) {
    const float* x    = (const float*)d_in[0];
    const int*   ei   = (const int*)d_in[1];
    const int*   batch= (const int*)d_in[2];
    const int*   cell = (const int*)d_in[3];
    const float* W1   = (const float*)d_in[4];
    const float* b1   = (const float*)d_in[5];
    const float* W2   = (const float*)d_in[6];
    const float* b2   = (const float*)d_in[7];
    const float* emb  = (const float*)d_in[8];
    const float* Wc   = (const float*)d_in[9];
    const float* bc   = (const float*)d_in[10];
    const float* lncw = (const float*)d_in[11];
    const float* lncb = (const float*)d_in[12];
    const float* Wf1  = (const float*)d_in[13];
    const float* bf1  = (const float*)d_in[14];
    const float* ln1w = (const float*)d_in[15];
    const float* ln1b = (const float*)d_in[16];
    const float* Wf2  = (const float*)d_in[17];
    const float* bf2  = (const float*)d_in[18];
    float* out = (float*)d_out;

    // workspace layout (256B aligned)
    char* ws = (char*)d_ws;
    size_t off = 0;
    auto alloc = [&](size_t bytes) { char* p = ws + off; off = (off + bytes + 255) & ~size_t(255); return p; };
    int*   degint = (int*)  alloc(N_NODES * 4);
    float* dinv   = (float*)alloc(N_NODES * 4);
    int*   rowptr = (int*)  alloc((N_NODES + 1) * 4);
    int*   cursor = (int*)  alloc(N_NODES * 4);
    int*   bsum   = (int*)  alloc(256 * 4);
    int*   boff   = (int*)  alloc(256 * 4);
    int*   colidx = (int*)  alloc(NEDGE * 4);
    unsigned short* hs = (unsigned short*)alloc((size_t)N_NODES * 128 * 2);
    float* nodebuf = (float*)alloc((size_t)N_NODES * 128 * 4);   // out1, then h2
    float* g       = (float*)alloc((size_t)NGRAPH * 128 * 4);

    const int nbScan = (N_NODES + 255) / 256;          // 196
    const int nbEdge = (NEDGE + 255) / 256;            // 3125
    const int nbGemm = (N_NODES + 63) / 64;            // 782
    const int nbAgg  = (N_NODES + 3) / 4;              // 12500 (4 waves/block)
    const int nbPool = (N_NODES + 127) / 128;          // 391

    hipMemsetAsync(degint, 0, N_NODES * 4, stream);
    hipMemsetAsync(g, 0, (size_t)NGRAPH * 128 * 4, stream);

    hist_kernel<<<nbEdge, 256, 0, stream>>>(ei, degint, NEDGE);
    dinv_kernel<<<nbScan, 256, 0, stream>>>(degint, dinv, N_NODES);
    scanA_kernel<<<nbScan, 256, 0, stream>>>(degint, rowptr, bsum, N_NODES);
    scanB_kernel<<<1, 256, 0, stream>>>(bsum, boff, rowptr, nbScan, N_NODES);
    scanC_kernel<<<nbScan, 256, 0, stream>>>(rowptr, cursor, boff, N_NODES);
    scatter_kernel<<<nbEdge, 256, 0, stream>>>(ei, cursor, colidx, NEDGE);

    // conv1
    gemm_scale_kernel<<<nbGemm, 256, 0, stream>>>(x, W1, dinv, hs, N_NODES);
    aggregate_kernel<<<nbAgg, 256, 0, stream>>>((const unsigned int*)hs, rowptr, colidx,
                                                dinv, b1, nodebuf, N_NODES);
    // conv2
    gemm_scale_kernel<<<nbGemm, 256, 0, stream>>>(nodebuf, W2, dinv, hs, N_NODES);
    aggregate_kernel<<<nbAgg, 256, 0, stream>>>((const unsigned int*)hs, rowptr, colidx,
                                                dinv, b2, nodebuf, N_NODES);
    // pool + tail
    pool_kernel<<<nbPool, 128, 0, stream>>>(nodebuf, batch, g, N_NODES);
    tail_kernel<<<NGRAPH, 128, 0, stream>>>(g, cell, emb, Wc, bc, lncw, lncb,
                                            Wf1, bf1, ln1w, ln1b, Wf2, bf2, out);
}

// Round 2
// 391.477 us; speedup vs baseline: 1.2440x; 1.2440x over previous
//
#include <hip/hip_runtime.h>

#define N_NODES 50000
#define NFEAT 128
#define NEDGE 800000
#define NGRAPH 512
#define NCE 64
#define EPS 1e-5f

// ---------- bf16 helpers (manual, bit-exact RNE) ----------
static __device__ __forceinline__ unsigned short f2bf(float f) {
    unsigned int u = __float_as_uint(f);
    unsigned int r = u + 0x7fffu + ((u >> 16) & 1u);
    return (unsigned short)(r >> 16);
}
static __device__ __forceinline__ float bf_lo(unsigned int packed) {
    return __uint_as_float(packed << 16);
}
static __device__ __forceinline__ float bf_hi(unsigned int packed) {
    return __uint_as_float(packed & 0xffff0000u);
}

// ---------- degree histogram ----------
__global__ void hist_kernel(const int* __restrict__ ei, int* __restrict__ degint, int E) {
    int e = blockIdx.x * blockDim.x + threadIdx.x;
    if (e < E) atomicAdd(&degint[ei[E + e]], 1);   // dst = ei[E+e]
}

// ---------- 3-phase exclusive scan over degint -> rowptr (+ dinv fused) ----------
__global__ void scanA_kernel(const int* __restrict__ cnt, int* __restrict__ rowptr,
                             int* __restrict__ bsum, float* __restrict__ dinv, int n) {
    __shared__ int s[256];
    int tid = threadIdx.x;
    int i = blockIdx.x * 256 + tid;
    int v = (i < n) ? cnt[i] : 0;
    if (i < n) dinv[i] = rsqrtf((float)v + 1.0f);
    s[tid] = v; __syncthreads();
    for (int off = 1; off < 256; off <<= 1) {
        int t = (tid >= off) ? s[tid - off] : 0;
        __syncthreads();
        s[tid] += t;
        __syncthreads();
    }
    if (i < n) rowptr[i] = s[tid] - v;        // local exclusive
    if (tid == 255) bsum[blockIdx.x] = s[255];
}
__global__ void scanB_kernel(const int* __restrict__ bsum, int* __restrict__ boff,
                             int* __restrict__ rowptr, int nb, int n) {
    __shared__ int s[256];
    int tid = threadIdx.x;
    int v = (tid < nb) ? bsum[tid] : 0;
    s[tid] = v; __syncthreads();
    for (int off = 1; off < 256; off <<= 1) {
        int t = (tid >= off) ? s[tid - off] : 0;
        __syncthreads();
        s[tid] += t;
        __syncthreads();
    }
    if (tid < nb) boff[tid] = s[tid] - v;     // exclusive
    if (tid == nb - 1) rowptr[n] = s[tid];    // total = E
}
__global__ void scanC_kernel(int* __restrict__ rowptr, int* __restrict__ cursor,
                             const int* __restrict__ boff, int n) {
    int i = blockIdx.x * 256 + threadIdx.x;
    if (i < n) {
        int r = rowptr[i] + boff[blockIdx.x];
        rowptr[i] = r;
        cursor[i] = r;
    }
}

// ---------- scatter edges into CSR buckets ----------
__global__ void scatter_kernel(const int* __restrict__ ei, int* __restrict__ cursor,
                               int* __restrict__ colidx, int E) {
    int e = blockIdx.x * blockDim.x + threadIdx.x;
    if (e < E) {
        int sv = ei[e];
        int dv = ei[E + e];
        int pos = atomicAdd(&cursor[dv], 1);
        colidx[pos] = sv;
    }
}

// ---------- GEMM: HS[r][c] = bf16( (X @ W)[r][c] * dinv[r] ) ----------
// block 256 threads, tile 64 rows x 128 cols, per-thread 8x4, K chunked by 32
__global__ __launch_bounds__(256) void gemm_scale_kernel(
    const float* __restrict__ X, const float* __restrict__ W,
    const float* __restrict__ dinv, unsigned short* __restrict__ HS, int nrows)
{
    __shared__ __align__(16) float xsT[32 * 72];   // [k][row], stride 72
    __shared__ __align__(16) float ws[32 * 128];   // [k][col]
    const int tid = threadIdx.x;
    const int row0 = blockIdx.x * 64;
    const int tc = tid & 31;    // col group: cols tc*4 .. tc*4+3
    const int tr = tid >> 5;    // row group: rows tr*8 .. tr*8+7
    float acc[8][4];
#pragma unroll
    for (int i = 0; i < 8; ++i)
#pragma unroll
        for (int j = 0; j < 4; ++j) acc[i][j] = 0.f;

    for (int kb = 0; kb < 128; kb += 32) {
        __syncthreads();
#pragma unroll
        for (int i = 0; i < 2; ++i) {
            int f4 = tid + i * 256;
            int r = f4 >> 3;          // 0..63
            int kq = f4 & 7;          // k/4
            int rr = row0 + r;
            if (rr >= nrows) rr = nrows - 1;
            const float4 v = *reinterpret_cast<const float4*>(&X[rr * 128 + kb + kq * 4]);
            xsT[(kq * 4 + 0) * 72 + r] = v.x;
            xsT[(kq * 4 + 1) * 72 + r] = v.y;
            xsT[(kq * 4 + 2) * 72 + r] = v.z;
            xsT[(kq * 4 + 3) * 72 + r] = v.w;
        }
#pragma unroll
        for (int i = 0; i < 4; ++i) {
            int f4 = tid + i * 256;
            int k = f4 >> 5, c4 = f4 & 31;
            *reinterpret_cast<float4*>(&ws[k * 128 + c4 * 4]) =
                *reinterpret_cast<const float4*>(&W[(kb + k) * 128 + c4 * 4]);
        }
        __syncthreads();
#pragma unroll
        for (int k = 0; k < 32; ++k) {
            const float4 a0 = *reinterpret_cast<const float4*>(&xsT[k * 72 + tr * 8]);
            const float4 a1 = *reinterpret_cast<const float4*>(&xsT[k * 72 + tr * 8 + 4]);
            const float4 bb = *reinterpret_cast<const float4*>(&ws[k * 128 + tc * 4]);
            float av[8] = {a0.x, a0.y, a0.z, a0.w, a1.x, a1.y, a1.z, a1.w};
            float bv[4] = {bb.x, bb.y, bb.z, bb.w};
#pragma unroll
            for (int i = 0; i < 8; ++i)
#pragma unroll
                for (int j = 0; j < 4; ++j)
                    acc[i][j] = fmaf(av[i], bv[j], acc[i][j]);
        }
    }
#pragma unroll
    for (int i = 0; i < 8; ++i) {
        int r = row0 + tr * 8 + i;
        if (r < nrows) {
            float s = dinv[r];
            ushort4 o;
            o.x = f2bf(acc[i][0] * s);
            o.y = f2bf(acc[i][1] * s);
            o.z = f2bf(acc[i][2] * s);
            o.w = f2bf(acc[i][3] * s);
            *reinterpret_cast<ushort4*>(&HS[r * 128 + tc * 4]) = o;
        }
    }
}

// ---------- aggregation v2: one wave per node, shfl-broadcast indices, 8-deep MLP ----------
// OUT[v] = relu( dinv[v] * (sum_{u in in(v)} HS[u] + HS[v]) + bias )
__global__ __launch_bounds__(256) void aggregate_kernel(
    const unsigned int* __restrict__ H,       // bf16x2 packed, [N][64]
    const int* __restrict__ rowptr, const int* __restrict__ colidx,
    const float* __restrict__ dinv, const float* __restrict__ bias,
    float* __restrict__ OUT, int n)
{
    int wid = (blockIdx.x * blockDim.x + threadIdx.x) >> 6;
    int lane = threadIdx.x & 63;
    if (wid >= n) return;
    unsigned int self = H[wid * 64 + lane];
    float a0 = bf_lo(self), a1 = bf_hi(self);
    float c0 = 0.f, c1 = 0.f, d0 = 0.f, d1 = 0.f, e0 = 0.f, e1 = 0.f;
    int beg = rowptr[wid], end = rowptr[wid + 1];
    for (int base = beg; base < end; base += 64) {
        int m = end - base; if (m > 64) m = 64;
        // one coalesced load fetches up to 64 neighbor indices for the wave
        int idx = (lane < m) ? colidx[base + lane] : 0;
        int j = 0;
        for (; j + 8 <= m; j += 8) {
            int u0 = __shfl(idx, j + 0);
            int u1 = __shfl(idx, j + 1);
            int u2 = __shfl(idx, j + 2);
            int u3 = __shfl(idx, j + 3);
            int u4 = __shfl(idx, j + 4);
            int u5 = __shfl(idx, j + 5);
            int u6 = __shfl(idx, j + 6);
            int u7 = __shfl(idx, j + 7);
            unsigned int t0 = H[u0 * 64 + lane];
            unsigned int t1 = H[u1 * 64 + lane];
            unsigned int t2 = H[u2 * 64 + lane];
            unsigned int t3 = H[u3 * 64 + lane];
            unsigned int t4 = H[u4 * 64 + lane];
            unsigned int t5 = H[u5 * 64 + lane];
            unsigned int t6 = H[u6 * 64 + lane];
            unsigned int t7 = H[u7 * 64 + lane];
            a0 += bf_lo(t0) + bf_lo(t4);
            a1 += bf_hi(t0) + bf_hi(t4);
            c0 += bf_lo(t1) + bf_lo(t5);
            c1 += bf_hi(t1) + bf_hi(t5);
            d0 += bf_lo(t2) + bf_lo(t6);
            d1 += bf_hi(t2) + bf_hi(t6);
            e0 += bf_lo(t3) + bf_lo(t7);
            e1 += bf_hi(t3) + bf_hi(t7);
        }
        for (; j + 2 <= m; j += 2) {
            int u0 = __shfl(idx, j + 0);
            int u1 = __shfl(idx, j + 1);
            unsigned int t0 = H[u0 * 64 + lane];
            unsigned int t1 = H[u1 * 64 + lane];
            a0 += bf_lo(t0); a1 += bf_hi(t0);
            c0 += bf_lo(t1); c1 += bf_hi(t1);
        }
        if (j < m) {
            int u0 = __shfl(idx, j);
            unsigned int t0 = H[u0 * 64 + lane];
            a0 += bf_lo(t0); a1 += bf_hi(t0);
        }
    }
    a0 += c0 + d0 + e0;
    a1 += c1 + d1 + e1;
    float s = dinv[wid];
    float b0 = bias[lane * 2 + 0];
    float b1 = bias[lane * 2 + 1];
    float2 o;
    o.x = fmaxf(fmaf(a0, s, b0), 0.f);
    o.y = fmaxf(fmaf(a1, s, b1), 0.f);
    *reinterpret_cast<float2*>(&OUT[wid * 128 + lane * 2]) = o;
}

// ---------- global add pool exploiting sorted batch ----------
__global__ __launch_bounds__(128) void pool_kernel(
    const float* __restrict__ H2, const int* __restrict__ batch,
    float* __restrict__ g, int n)
{
    int j = threadIdx.x;
    int n0 = blockIdx.x * 128;
    int n1 = min(n0 + 128, n);
    if (n0 >= n) return;
    float acc = 0.f;
    int cur = batch[n0];
    for (int v = n0; v < n1; ++v) {
        int b = batch[v];
        if (b != cur) {
            atomicAdd(&g[cur * 128 + j], acc);
            acc = 0.f;
            cur = b;
        }
        acc += H2[v * 128 + j];
    }
    atomicAdd(&g[cur * 128 + j], acc);
}

// ---------- fused tail: concat -> fc+LN+relu -> fc+relu -> LN -> fc ----------
static __device__ __forceinline__ float block_ln(float x, float w, float b,
                                                 float* red, int j, bool relu_after) {
    red[j] = x; __syncthreads();
    for (int off = 64; off > 0; off >>= 1) {
        if (j < off) red[j] += red[j + off];
        __syncthreads();
    }
    float mu = red[0] * (1.f / 128.f);
    __syncthreads();
    float d = x - mu;
    red[j] = d * d; __syncthreads();
    for (int off = 64; off > 0; off >>= 1) {
        if (j < off) red[j] += red[j + off];
        __syncthreads();
    }
    float var = red[0] * (1.f / 128.f);
    __syncthreads();
    float y = d * rsqrtf(var + EPS) * w + b;
    return relu_after ? fmaxf(y, 0.f) : y;
}

__global__ __launch_bounds__(128) void tail_kernel(
    const float* __restrict__ g, const int* __restrict__ cell,
    const float* __restrict__ emb,
    const float* __restrict__ Wc, const float* __restrict__ bc,
    const float* __restrict__ lncw, const float* __restrict__ lncb,
    const float* __restrict__ Wf1, const float* __restrict__ bf1,
    const float* __restrict__ ln1w, const float* __restrict__ ln1b,
    const float* __restrict__ Wf2, const float* __restrict__ bf2,
    float* __restrict__ out)
{
    __shared__ float comb[192];
    __shared__ float red[128];
    __shared__ float vec[128];
    int gi = blockIdx.x, j = threadIdx.x;
    comb[j] = g[gi * 128 + j];
    if (j < 64) comb[128 + j] = emb[cell[gi] * 64 + j];
    __syncthreads();
    float acc = bc[j];
#pragma unroll 4
    for (int k = 0; k < 192; ++k) acc = fmaf(comb[k], Wc[k * 128 + j], acc);
    acc = block_ln(acc, lncw[j], lncb[j], red, j, true);
    vec[j] = acc; __syncthreads();
    float acc2 = bf1[j];
#pragma unroll 4
    for (int k = 0; k < 128; ++k) acc2 = fmaf(vec[k], Wf1[k * 128 + j], acc2);
    acc2 = fmaxf(acc2, 0.f);
    acc2 = block_ln(acc2, ln1w[j], ln1b[j], red, j, false);
    __syncthreads();
    vec[j] = acc2; __syncthreads();
    float acc3 = bf2[j];
#pragma unroll 4
    for (int k = 0; k < 128; ++k) acc3 = fmaf(vec[k], Wf2[k * 128 + j], acc3);
    out[gi * 128 + j] = acc3;
}

// ---------- host launch ----------
extern "C" void kernel_launch(void* const* d_in, const int* in_sizes, int n_in,
                              void* d_out, int out_size, void* d_ws, size_t ws_size,
                              hipStream_t stream) {
    const float* x    = (const float*)d_in[0];
    const int*   ei   = (const int*)d_in[1];
    const int*   batch= (const int*)d_in[2];
    const int*   cell = (const int*)d_in[3];
    const float* W1   = (const float*)d_in[4];
    const float* b1   = (const float*)d_in[5];
    const float* W2   = (const float*)d_in[6];
    const float* b2   = (const float*)d_in[7];
    const float* emb  = (const float*)d_in[8];
    const float* Wc   = (const float*)d_in[9];
    const float* bc   = (const float*)d_in[10];
    const float* lncw = (const float*)d_in[11];
    const float* lncb = (const float*)d_in[12];
    const float* Wf1  = (const float*)d_in[13];
    const float* bf1  = (const float*)d_in[14];
    const float* ln1w = (const float*)d_in[15];
    const float* ln1b = (const float*)d_in[16];
    const float* Wf2  = (const float*)d_in[17];
    const float* bf2  = (const float*)d_in[18];
    float* out = (float*)d_out;

    char* ws = (char*)d_ws;
    size_t off = 0;
    auto alloc = [&](size_t bytes) { char* p = ws + off; off = (off + bytes + 255) & ~size_t(255); return p; };
    int*   degint = (int*)  alloc(N_NODES * 4);
    float* dinv   = (float*)alloc(N_NODES * 4);
    int*   rowptr = (int*)  alloc((N_NODES + 1) * 4);
    int*   cursor = (int*)  alloc(N_NODES * 4);
    int*   bsum   = (int*)  alloc(256 * 4);
    int*   boff   = (int*)  alloc(256 * 4);
    int*   colidx = (int*)  alloc(NEDGE * 4);
    unsigned short* hs = (unsigned short*)alloc((size_t)N_NODES * 128 * 2);
    float* nodebuf = (float*)alloc((size_t)N_NODES * 128 * 4);
    float* g       = (float*)alloc((size_t)NGRAPH * 128 * 4);

    const int nbScan = (N_NODES + 255) / 256;          // 196
    const int nbEdge = (NEDGE + 255) / 256;            // 3125
    const int nbGemm = (N_NODES + 63) / 64;            // 782
    const int nbAgg  = (N_NODES + 3) / 4;              // 12500 (4 waves/block)
    const int nbPool = (N_NODES + 127) / 128;          // 391

    hipMemsetAsync(degint, 0, N_NODES * 4, stream);
    hipMemsetAsync(g, 0, (size_t)NGRAPH * 128 * 4, stream);

    hist_kernel<<<nbEdge, 256, 0, stream>>>(ei, degint, NEDGE);
    scanA_kernel<<<nbScan, 256, 0, stream>>>(degint, rowptr, bsum, dinv, N_NODES);
    scanB_kernel<<<1, 256, 0, stream>>>(bsum, boff, rowptr, nbScan, N_NODES);
    scanC_kernel<<<nbScan, 256, 0, stream>>>(rowptr, cursor, boff, N_NODES);
    scatter_kernel<<<nbEdge, 256, 0, stream>>>(ei, cursor, colidx, NEDGE);

    // conv1
    gemm_scale_kernel<<<nbGemm, 256, 0, stream>>>(x, W1, dinv, hs, N_NODES);
    aggregate_kernel<<<nbAgg, 256, 0, stream>>>((const unsigned int*)hs, rowptr, colidx,
                                                dinv, b1, nodebuf, N_NODES);
    // conv2
    gemm_scale_kernel<<<nbGemm, 256, 0, stream>>>(nodebuf, W2, dinv, hs, N_NODES);
    aggregate_kernel<<<nbAgg, 256, 0, stream>>>((const unsigned int*)hs, rowptr, colidx,
                                                dinv, b2, nodebuf, N_NODES);
    // pool + tail
    pool_kernel<<<nbPool, 128, 0, stream>>>(nodebuf, batch, g, N_NODES);
    tail_kernel<<<NGRAPH, 128, 0, stream>>>(g, cell, emb, Wc, bc, lncw, lncb,
                                            Wf1, bf1, ln1w, ln1b, Wf2, bf2, out);
}

// Round 3
// 330.483 us; speedup vs baseline: 1.4735x; 1.1846x over previous
//
#include <hip/hip_runtime.h>

#define N_NODES 50000
#define NFEAT 128
#define NEDGE 800000
#define NGRAPH 512
#define NCE 64
#define EPS 1e-5f
#define NBUCK 196            // ceil(50000/256) buckets of 256 nodes
#define EPB 4096             // edges per bucket_scatter block
#define CSR_STAGE_CAP 8192   // LDS staging entries in bucket_csr

// ---------- bf16 helpers (manual, bit-exact RNE) ----------
static __device__ __forceinline__ unsigned short f2bf(float f) {
    unsigned int u = __float_as_uint(f);
    unsigned int r = u + 0x7fffu + ((u >> 16) & 1u);
    return (unsigned short)(r >> 16);
}
static __device__ __forceinline__ float bf_lo(unsigned int packed) {
    return __uint_as_float(packed << 16);
}
static __device__ __forceinline__ float bf_hi(unsigned int packed) {
    return __uint_as_float(packed & 0xffff0000u);
}

// ---------- 1. bucket histogram: LDS hist, 196 global atomics per block ----------
__global__ __launch_bounds__(256) void bucket_hist_kernel(
    const int* __restrict__ ei, int* __restrict__ bucketCnt, int E)
{
    __shared__ int hist[NBUCK];
    int tid = threadIdx.x;
    if (tid < NBUCK) hist[tid] = 0;
    __syncthreads();
    int e0 = blockIdx.x * EPB + tid;
#pragma unroll
    for (int i = 0; i < EPB / 256; ++i) {
        int e = e0 + i * 256;
        if (e < E) atomicAdd(&hist[ei[E + e] >> 8], 1);
    }
    __syncthreads();
    if (tid < NBUCK && hist[tid] > 0) atomicAdd(&bucketCnt[tid], hist[tid]);
}

// ---------- 2. scan bucket counts -> bases, init cursors ----------
__global__ __launch_bounds__(256) void bucket_scan_kernel(
    const int* __restrict__ bucketCnt, int* __restrict__ bucketBase,
    int* __restrict__ bucketCursor, int* __restrict__ rowptr)
{
    __shared__ int s[256];
    int tid = threadIdx.x;
    int v = (tid < NBUCK) ? bucketCnt[tid] : 0;
    s[tid] = v; __syncthreads();
    for (int off = 1; off < 256; off <<= 1) {
        int t = (tid >= off) ? s[tid - off] : 0;
        __syncthreads();
        s[tid] += t;
        __syncthreads();
    }
    int excl = s[tid] - v;
    if (tid <= NBUCK) bucketBase[tid] = excl;
    if (tid < NBUCK) bucketCursor[tid] = excl;
    if (tid == NBUCK) rowptr[N_NODES] = excl;   // == E
}

// ---------- 3. bucket scatter: LDS-partition 4096 edges, stream bucket-sorted ----------
__global__ __launch_bounds__(256) void bucket_scatter_kernel(
    const int* __restrict__ ei, int* __restrict__ bucketCursor,
    uint2* __restrict__ recbuf, int E)
{
    __shared__ int hist[NBUCK];
    __shared__ int lbase[NBUCK];   // local exclusive offsets
    __shared__ int gbase[NBUCK];   // reserved global offsets
    __shared__ int cur[NBUCK];
    __shared__ int scanbuf[256];
    __shared__ uint2 staging[EPB];
    int tid = threadIdx.x;
    if (tid < NBUCK) { hist[tid] = 0; cur[tid] = 0; }
    __syncthreads();

    uint2 rec[EPB / 256];
    int e0 = blockIdx.x * EPB + tid;
#pragma unroll
    for (int i = 0; i < EPB / 256; ++i) {
        int e = e0 + i * 256;
        if (e < E) {
            rec[i].x = (unsigned)ei[e];        // src
            rec[i].y = (unsigned)ei[E + e];    // dst
            atomicAdd(&hist[rec[i].y >> 8], 1);
        } else {
            rec[i].y = 0xffffffffu;            // invalid marker
        }
    }
    __syncthreads();
    // scan hist (196 padded to 256)
    int v = (tid < NBUCK) ? hist[tid] : 0;
    scanbuf[tid] = v; __syncthreads();
    for (int off = 1; off < 256; off <<= 1) {
        int t = (tid >= off) ? scanbuf[tid - off] : 0;
        __syncthreads();
        scanbuf[tid] += t;
        __syncthreads();
    }
    if (tid < NBUCK) lbase[tid] = scanbuf[tid] - v;
    int total = scanbuf[255];
    // reserve global ranges: one atomic per bucket per block
    if (tid < NBUCK) gbase[tid] = (v > 0) ? atomicAdd(&bucketCursor[tid], v) : 0;
    __syncthreads();
    // partition into staging (bucket-sorted within block)
#pragma unroll
    for (int i = 0; i < EPB / 256; ++i) {
        if (rec[i].y != 0xffffffffu) {
            int b = rec[i].y >> 8;
            int loc = atomicAdd(&cur[b], 1);
            staging[lbase[b] + loc] = rec[i];
        }
    }
    __syncthreads();
    // stream out: consecutive staged slots within a bucket -> consecutive global
    for (int s = tid; s < total; s += 256) {
        uint2 r = staging[s];
        int b = r.y >> 8;
        recbuf[gbase[b] + (s - lbase[b])] = r;
    }
}

// ---------- 4. per-bucket CSR finalize: rowptr + dinv + coalesced colidx ----------
__global__ __launch_bounds__(256) void bucket_csr_kernel(
    const uint2* __restrict__ recbuf, const int* __restrict__ bucketBase,
    int* __restrict__ rowptr, float* __restrict__ dinv,
    int* __restrict__ colidx)
{
    __shared__ int cnt[256];
    __shared__ int cur[256];
    __shared__ int scanbuf[256];
    __shared__ int stage[CSR_STAGE_CAP];
    int b = blockIdx.x, tid = threadIdx.x;
    int base = bucketBase[b];
    int len = bucketBase[b + 1] - base;
    cnt[tid] = 0;
    __syncthreads();
    // count per node
    for (int s = tid; s < len; s += 256) {
        uint2 r = recbuf[base + s];
        atomicAdd(&cnt[r.y & 255], 1);
    }
    __syncthreads();
    int v = cnt[tid];
    scanbuf[tid] = v; __syncthreads();
    for (int off = 1; off < 256; off <<= 1) {
        int t = (tid >= off) ? scanbuf[tid - off] : 0;
        __syncthreads();
        scanbuf[tid] += t;
        __syncthreads();
    }
    int excl = scanbuf[tid] - v;
    int node = b * 256 + tid;
    if (node < N_NODES) {
        rowptr[node] = base + excl;
        dinv[node] = rsqrtf((float)v + 1.0f);
    }
    cur[tid] = excl;
    __syncthreads();
    // scatter src into LDS staging at final (bucket-relative) positions
    for (int s = tid; s < len; s += 256) {
        uint2 r = recbuf[base + s];
        int pos = atomicAdd(&cur[r.y & 255], 1);
        if (pos < CSR_STAGE_CAP) stage[pos] = (int)r.x;
        else colidx[base + pos] = (int)r.x;   // overflow fallback (never in practice)
    }
    __syncthreads();
    int m = (len < CSR_STAGE_CAP) ? len : CSR_STAGE_CAP;
    for (int s = tid; s < m; s += 256) colidx[base + s] = stage[s];
}

// ---------- GEMM: HS[r][c] = bf16( (X @ W)[r][c] * dinv[r] ) ----------
__global__ __launch_bounds__(256) void gemm_scale_kernel(
    const float* __restrict__ X, const float* __restrict__ W,
    const float* __restrict__ dinv, unsigned short* __restrict__ HS, int nrows)
{
    __shared__ __align__(16) float xsT[32 * 72];
    __shared__ __align__(16) float ws[32 * 128];
    const int tid = threadIdx.x;
    const int row0 = blockIdx.x * 64;
    const int tc = tid & 31;
    const int tr = tid >> 5;
    float acc[8][4];
#pragma unroll
    for (int i = 0; i < 8; ++i)
#pragma unroll
        for (int j = 0; j < 4; ++j) acc[i][j] = 0.f;

    for (int kb = 0; kb < 128; kb += 32) {
        __syncthreads();
#pragma unroll
        for (int i = 0; i < 2; ++i) {
            int f4 = tid + i * 256;
            int r = f4 >> 3;
            int kq = f4 & 7;
            int rr = row0 + r;
            if (rr >= nrows) rr = nrows - 1;
            const float4 v = *reinterpret_cast<const float4*>(&X[rr * 128 + kb + kq * 4]);
            xsT[(kq * 4 + 0) * 72 + r] = v.x;
            xsT[(kq * 4 + 1) * 72 + r] = v.y;
            xsT[(kq * 4 + 2) * 72 + r] = v.z;
            xsT[(kq * 4 + 3) * 72 + r] = v.w;
        }
#pragma unroll
        for (int i = 0; i < 4; ++i) {
            int f4 = tid + i * 256;
            int k = f4 >> 5, c4 = f4 & 31;
            *reinterpret_cast<float4*>(&ws[k * 128 + c4 * 4]) =
                *reinterpret_cast<const float4*>(&W[(kb + k) * 128 + c4 * 4]);
        }
        __syncthreads();
#pragma unroll
        for (int k = 0; k < 32; ++k) {
            const float4 a0 = *reinterpret_cast<const float4*>(&xsT[k * 72 + tr * 8]);
            const float4 a1 = *reinterpret_cast<const float4*>(&xsT[k * 72 + tr * 8 + 4]);
            const float4 bb = *reinterpret_cast<const float4*>(&ws[k * 128 + tc * 4]);
            float av[8] = {a0.x, a0.y, a0.z, a0.w, a1.x, a1.y, a1.z, a1.w};
            float bv[4] = {bb.x, bb.y, bb.z, bb.w};
#pragma unroll
            for (int i = 0; i < 8; ++i)
#pragma unroll
                for (int j = 0; j < 4; ++j)
                    acc[i][j] = fmaf(av[i], bv[j], acc[i][j]);
        }
    }
#pragma unroll
    for (int i = 0; i < 8; ++i) {
        int r = row0 + tr * 8 + i;
        if (r < nrows) {
            float s = dinv[r];
            ushort4 o;
            o.x = f2bf(acc[i][0] * s);
            o.y = f2bf(acc[i][1] * s);
            o.z = f2bf(acc[i][2] * s);
            o.w = f2bf(acc[i][3] * s);
            *reinterpret_cast<ushort4*>(&HS[r * 128 + tc * 4]) = o;
        }
    }
}

// ---------- aggregation: one wave per node, shfl-broadcast indices, 8-deep MLP ----------
__global__ __launch_bounds__(256) void aggregate_kernel(
    const unsigned int* __restrict__ H,
    const int* __restrict__ rowptr, const int* __restrict__ colidx,
    const float* __restrict__ dinv, const float* __restrict__ bias,
    float* __restrict__ OUT, int n)
{
    int wid = (blockIdx.x * blockDim.x + threadIdx.x) >> 6;
    int lane = threadIdx.x & 63;
    if (wid >= n) return;
    unsigned int self = H[wid * 64 + lane];
    float a0 = bf_lo(self), a1 = bf_hi(self);
    float c0 = 0.f, c1 = 0.f, d0 = 0.f, d1 = 0.f, e0 = 0.f, e1 = 0.f;
    int beg = rowptr[wid], end = rowptr[wid + 1];
    for (int base = beg; base < end; base += 64) {
        int m = end - base; if (m > 64) m = 64;
        int idx = (lane < m) ? colidx[base + lane] : 0;
        int j = 0;
        for (; j + 8 <= m; j += 8) {
            int u0 = __shfl(idx, j + 0);
            int u1 = __shfl(idx, j + 1);
            int u2 = __shfl(idx, j + 2);
            int u3 = __shfl(idx, j + 3);
            int u4 = __shfl(idx, j + 4);
            int u5 = __shfl(idx, j + 5);
            int u6 = __shfl(idx, j + 6);
            int u7 = __shfl(idx, j + 7);
            unsigned int t0 = H[u0 * 64 + lane];
            unsigned int t1 = H[u1 * 64 + lane];
            unsigned int t2 = H[u2 * 64 + lane];
            unsigned int t3 = H[u3 * 64 + lane];
            unsigned int t4 = H[u4 * 64 + lane];
            unsigned int t5 = H[u5 * 64 + lane];
            unsigned int t6 = H[u6 * 64 + lane];
            unsigned int t7 = H[u7 * 64 + lane];
            a0 += bf_lo(t0) + bf_lo(t4);
            a1 += bf_hi(t0) + bf_hi(t4);
            c0 += bf_lo(t1) + bf_lo(t5);
            c1 += bf_hi(t1) + bf_hi(t5);
            d0 += bf_lo(t2) + bf_lo(t6);
            d1 += bf_hi(t2) + bf_hi(t6);
            e0 += bf_lo(t3) + bf_lo(t7);
            e1 += bf_hi(t3) + bf_hi(t7);
        }
        for (; j + 2 <= m; j += 2) {
            int u0 = __shfl(idx, j + 0);
            int u1 = __shfl(idx, j + 1);
            unsigned int t0 = H[u0 * 64 + lane];
            unsigned int t1 = H[u1 * 64 + lane];
            a0 += bf_lo(t0); a1 += bf_hi(t0);
            c0 += bf_lo(t1); c1 += bf_hi(t1);
        }
        if (j < m) {
            int u0 = __shfl(idx, j);
            unsigned int t0 = H[u0 * 64 + lane];
            a0 += bf_lo(t0); a1 += bf_hi(t0);
        }
    }
    a0 += c0 + d0 + e0;
    a1 += c1 + d1 + e1;
    float s = dinv[wid];
    float b0 = bias[lane * 2 + 0];
    float b1 = bias[lane * 2 + 1];
    float2 o;
    o.x = fmaxf(fmaf(a0, s, b0), 0.f);
    o.y = fmaxf(fmaf(a1, s, b1), 0.f);
    *reinterpret_cast<float2*>(&OUT[wid * 128 + lane * 2]) = o;
}

// ---------- global add pool exploiting sorted batch ----------
__global__ __launch_bounds__(128) void pool_kernel(
    const float* __restrict__ H2, const int* __restrict__ batch,
    float* __restrict__ g, int n)
{
    int j = threadIdx.x;
    int n0 = blockIdx.x * 128;
    int n1 = min(n0 + 128, n);
    if (n0 >= n) return;
    float acc = 0.f;
    int cur = batch[n0];
    for (int v = n0; v < n1; ++v) {
        int b = batch[v];
        if (b != cur) {
            atomicAdd(&g[cur * 128 + j], acc);
            acc = 0.f;
            cur = b;
        }
        acc += H2[v * 128 + j];
    }
    atomicAdd(&g[cur * 128 + j], acc);
}

// ---------- fused tail ----------
static __device__ __forceinline__ float block_ln(float x, float w, float b,
                                                 float* red, int j, bool relu_after) {
    red[j] = x; __syncthreads();
    for (int off = 64; off > 0; off >>= 1) {
        if (j < off) red[j] += red[j + off];
        __syncthreads();
    }
    float mu = red[0] * (1.f / 128.f);
    __syncthreads();
    float d = x - mu;
    red[j] = d * d; __syncthreads();
    for (int off = 64; off > 0; off >>= 1) {
        if (j < off) red[j] += red[j + off];
        __syncthreads();
    }
    float var = red[0] * (1.f / 128.f);
    __syncthreads();
    float y = d * rsqrtf(var + EPS) * w + b;
    return relu_after ? fmaxf(y, 0.f) : y;
}

__global__ __launch_bounds__(128) void tail_kernel(
    const float* __restrict__ g, const int* __restrict__ cell,
    const float* __restrict__ emb,
    const float* __restrict__ Wc, const float* __restrict__ bc,
    const float* __restrict__ lncw, const float* __restrict__ lncb,
    const float* __restrict__ Wf1, const float* __restrict__ bf1,
    const float* __restrict__ ln1w, const float* __restrict__ ln1b,
    const float* __restrict__ Wf2, const float* __restrict__ bf2,
    float* __restrict__ out)
{
    __shared__ float comb[192];
    __shared__ float red[128];
    __shared__ float vec[128];
    int gi = blockIdx.x, j = threadIdx.x;
    comb[j] = g[gi * 128 + j];
    if (j < 64) comb[128 + j] = emb[cell[gi] * 64 + j];
    __syncthreads();
    float acc = bc[j];
#pragma unroll 4
    for (int k = 0; k < 192; ++k) acc = fmaf(comb[k], Wc[k * 128 + j], acc);
    acc = block_ln(acc, lncw[j], lncb[j], red, j, true);
    vec[j] = acc; __syncthreads();
    float acc2 = bf1[j];
#pragma unroll 4
    for (int k = 0; k < 128; ++k) acc2 = fmaf(vec[k], Wf1[k * 128 + j], acc2);
    acc2 = fmaxf(acc2, 0.f);
    acc2 = block_ln(acc2, ln1w[j], ln1b[j], red, j, false);
    __syncthreads();
    vec[j] = acc2; __syncthreads();
    float acc3 = bf2[j];
#pragma unroll 4
    for (int k = 0; k < 128; ++k) acc3 = fmaf(vec[k], Wf2[k * 128 + j], acc3);
    out[gi * 128 + j] = acc3;
}

// ---------- host launch ----------
extern "C" void kernel_launch(void* const* d_in, const int* in_sizes, int n_in,
                              void* d_out, int out_size, void* d_ws, size_t ws_size,
                              hipStream_t stream) {
    const float* x    = (const float*)d_in[0];
    const int*   ei   = (const int*)d_in[1];
    const int*   batch= (const int*)d_in[2];
    const int*   cell = (const int*)d_in[3];
    const float* W1   = (const float*)d_in[4];
    const float* b1   = (const float*)d_in[5];
    const float* W2   = (const float*)d_in[6];
    const float* b2   = (const float*)d_in[7];
    const float* emb  = (const float*)d_in[8];
    const float* Wc   = (const float*)d_in[9];
    const float* bc   = (const float*)d_in[10];
    const float* lncw = (const float*)d_in[11];
    const float* lncb = (const float*)d_in[12];
    const float* Wf1  = (const float*)d_in[13];
    const float* bf1  = (const float*)d_in[14];
    const float* ln1w = (const float*)d_in[15];
    const float* ln1b = (const float*)d_in[16];
    const float* Wf2  = (const float*)d_in[17];
    const float* bf2  = (const float*)d_in[18];
    float* out = (float*)d_out;

    char* ws = (char*)d_ws;
    size_t off = 0;
    auto alloc = [&](size_t bytes) { char* p = ws + off; off = (off + bytes + 255) & ~size_t(255); return p; };
    float* dinv       = (float*)alloc(N_NODES * 4);
    int*   rowptr     = (int*)  alloc((N_NODES + 1) * 4);
    int*   colidx     = (int*)  alloc(NEDGE * 4);
    int*   bucketCnt  = (int*)  alloc(NBUCK * 4);
    int*   bucketBase = (int*)  alloc((NBUCK + 1) * 4);
    int*   bucketCursor=(int*)  alloc(NBUCK * 4);
    uint2* recbuf     = (uint2*)alloc((size_t)NEDGE * 8);
    unsigned short* hs = (unsigned short*)alloc((size_t)N_NODES * 128 * 2);
    float* nodebuf    = (float*)alloc((size_t)N_NODES * 128 * 4);
    float* g          = (float*)alloc((size_t)NGRAPH * 128 * 4);

    const int nbEdge = (NEDGE + EPB - 1) / EPB;        // 196
    const int nbGemm = (N_NODES + 63) / 64;            // 782
    const int nbAgg  = (N_NODES + 3) / 4;              // 12500
    const int nbPool = (N_NODES + 127) / 128;          // 391

    hipMemsetAsync(bucketCnt, 0, NBUCK * 4, stream);
    hipMemsetAsync(g, 0, (size_t)NGRAPH * 128 * 4, stream);

    // CSR build (atomic-light, coalesced writes)
    bucket_hist_kernel<<<nbEdge, 256, 0, stream>>>(ei, bucketCnt, NEDGE);
    bucket_scan_kernel<<<1, 256, 0, stream>>>(bucketCnt, bucketBase, bucketCursor, rowptr);
    bucket_scatter_kernel<<<nbEdge, 256, 0, stream>>>(ei, bucketCursor, recbuf, NEDGE);
    bucket_csr_kernel<<<NBUCK, 256, 0, stream>>>(recbuf, bucketBase, rowptr, dinv, colidx);

    // conv1
    gemm_scale_kernel<<<nbGemm, 256, 0, stream>>>(x, W1, dinv, hs, N_NODES);
    aggregate_kernel<<<nbAgg, 256, 0, stream>>>((const unsigned int*)hs, rowptr, colidx,
                                                dinv, b1, nodebuf, N_NODES);
    // conv2
    gemm_scale_kernel<<<nbGemm, 256, 0, stream>>>(nodebuf, W2, dinv, hs, N_NODES);
    aggregate_kernel<<<nbAgg, 256, 0, stream>>>((const unsigned int*)hs, rowptr, colidx,
                                                dinv, b2, nodebuf, N_NODES);
    // pool + tail
    pool_kernel<<<nbPool, 128, 0, stream>>>(nodebuf, batch, g, N_NODES);
    tail_kernel<<<NGRAPH, 128, 0, stream>>>(g, cell, emb, Wc, bc, lncw, lncb,
                                            Wf1, bf1, ln1w, ln1b, Wf2, bf2, out);
}

// Round 4
// 314.025 us; speedup vs baseline: 1.5508x; 1.0524x over previous
//
#include <hip/hip_runtime.h>

#define N_NODES 50000
#define NFEAT 128
#define NEDGE 800000
#define NGRAPH 512
#define NCE 64
#define EPS 1e-5f
#define NBUCK 196            // ceil(50000/256) buckets of 256 nodes
#define EPB 4096             // edges per bucket_scatter block
#define CSR_STAGE_CAP 8192   // LDS staging entries in bucket_csr

// ---------- bf16 helpers (manual, bit-exact RNE) ----------
static __device__ __forceinline__ unsigned short f2bf(float f) {
    unsigned int u = __float_as_uint(f);
    unsigned int r = u + 0x7fffu + ((u >> 16) & 1u);
    return (unsigned short)(r >> 16);
}
static __device__ __forceinline__ float bf_lo(unsigned int packed) {
    return __uint_as_float(packed << 16);
}
static __device__ __forceinline__ float bf_hi(unsigned int packed) {
    return __uint_as_float(packed & 0xffff0000u);
}

// ---------- 1. bucket histogram ----------
__global__ __launch_bounds__(256) void bucket_hist_kernel(
    const int* __restrict__ ei, int* __restrict__ bucketCnt, int E)
{
    __shared__ int hist[NBUCK];
    int tid = threadIdx.x;
    if (tid < NBUCK) hist[tid] = 0;
    __syncthreads();
    int e0 = blockIdx.x * EPB + tid;
#pragma unroll
    for (int i = 0; i < EPB / 256; ++i) {
        int e = e0 + i * 256;
        if (e < E) atomicAdd(&hist[ei[E + e] >> 8], 1);
    }
    __syncthreads();
    if (tid < NBUCK && hist[tid] > 0) atomicAdd(&bucketCnt[tid], hist[tid]);
}

// ---------- 2. scan bucket counts ----------
__global__ __launch_bounds__(256) void bucket_scan_kernel(
    const int* __restrict__ bucketCnt, int* __restrict__ bucketBase,
    int* __restrict__ bucketCursor, int* __restrict__ rowptr)
{
    __shared__ int s[256];
    int tid = threadIdx.x;
    int v = (tid < NBUCK) ? bucketCnt[tid] : 0;
    s[tid] = v; __syncthreads();
    for (int off = 1; off < 256; off <<= 1) {
        int t = (tid >= off) ? s[tid - off] : 0;
        __syncthreads();
        s[tid] += t;
        __syncthreads();
    }
    int excl = s[tid] - v;
    if (tid <= NBUCK) bucketBase[tid] = excl;
    if (tid < NBUCK) bucketCursor[tid] = excl;
    if (tid == NBUCK) rowptr[N_NODES] = excl;   // == E
}

// ---------- 3. bucket scatter ----------
__global__ __launch_bounds__(256) void bucket_scatter_kernel(
    const int* __restrict__ ei, int* __restrict__ bucketCursor,
    uint2* __restrict__ recbuf, int E)
{
    __shared__ int hist[NBUCK];
    __shared__ int lbase[NBUCK];
    __shared__ int gbase[NBUCK];
    __shared__ int cur[NBUCK];
    __shared__ int scanbuf[256];
    __shared__ uint2 staging[EPB];
    int tid = threadIdx.x;
    if (tid < NBUCK) { hist[tid] = 0; cur[tid] = 0; }
    __syncthreads();

    uint2 rec[EPB / 256];
    int e0 = blockIdx.x * EPB + tid;
#pragma unroll
    for (int i = 0; i < EPB / 256; ++i) {
        int e = e0 + i * 256;
        if (e < E) {
            rec[i].x = (unsigned)ei[e];
            rec[i].y = (unsigned)ei[E + e];
            atomicAdd(&hist[rec[i].y >> 8], 1);
        } else {
            rec[i].y = 0xffffffffu;
        }
    }
    __syncthreads();
    int v = (tid < NBUCK) ? hist[tid] : 0;
    scanbuf[tid] = v; __syncthreads();
    for (int off = 1; off < 256; off <<= 1) {
        int t = (tid >= off) ? scanbuf[tid - off] : 0;
        __syncthreads();
        scanbuf[tid] += t;
        __syncthreads();
    }
    if (tid < NBUCK) lbase[tid] = scanbuf[tid] - v;
    int total = scanbuf[255];
    if (tid < NBUCK) gbase[tid] = (v > 0) ? atomicAdd(&bucketCursor[tid], v) : 0;
    __syncthreads();
#pragma unroll
    for (int i = 0; i < EPB / 256; ++i) {
        if (rec[i].y != 0xffffffffu) {
            int b = rec[i].y >> 8;
            int loc = atomicAdd(&cur[b], 1);
            staging[lbase[b] + loc] = rec[i];
        }
    }
    __syncthreads();
    for (int s = tid; s < total; s += 256) {
        uint2 r = staging[s];
        int b = r.y >> 8;
        recbuf[gbase[b] + (s - lbase[b])] = r;
    }
}

// ---------- 4. per-bucket CSR finalize ----------
__global__ __launch_bounds__(256) void bucket_csr_kernel(
    const uint2* __restrict__ recbuf, const int* __restrict__ bucketBase,
    int* __restrict__ rowptr, float* __restrict__ dinv,
    int* __restrict__ colidx)
{
    __shared__ int cnt[256];
    __shared__ int cur[256];
    __shared__ int scanbuf[256];
    __shared__ int stage[CSR_STAGE_CAP];
    int b = blockIdx.x, tid = threadIdx.x;
    int base = bucketBase[b];
    int len = bucketBase[b + 1] - base;
    cnt[tid] = 0;
    __syncthreads();
    for (int s = tid; s < len; s += 256) {
        uint2 r = recbuf[base + s];
        atomicAdd(&cnt[r.y & 255], 1);
    }
    __syncthreads();
    int v = cnt[tid];
    scanbuf[tid] = v; __syncthreads();
    for (int off = 1; off < 256; off <<= 1) {
        int t = (tid >= off) ? scanbuf[tid - off] : 0;
        __syncthreads();
        scanbuf[tid] += t;
        __syncthreads();
    }
    int excl = scanbuf[tid] - v;
    int node = b * 256 + tid;
    if (node < N_NODES) {
        rowptr[node] = base + excl;
        dinv[node] = rsqrtf((float)v + 1.0f);
    }
    cur[tid] = excl;
    __syncthreads();
    for (int s = tid; s < len; s += 256) {
        uint2 r = recbuf[base + s];
        int pos = atomicAdd(&cur[r.y & 255], 1);
        if (pos < CSR_STAGE_CAP) stage[pos] = (int)r.x;
        else colidx[base + pos] = (int)r.x;
    }
    __syncthreads();
    int m = (len < CSR_STAGE_CAP) ? len : CSR_STAGE_CAP;
    for (int s = tid; s < m; s += 256) colidx[base + s] = stage[s];
}

// ---------- GEMM: HS[r][c] = bf16( (X @ W)[r][c] * dinv[r] ) ----------
__global__ __launch_bounds__(256) void gemm_scale_kernel(
    const float* __restrict__ X, const float* __restrict__ W,
    const float* __restrict__ dinv, unsigned short* __restrict__ HS, int nrows)
{
    __shared__ __align__(16) float xsT[32 * 72];
    __shared__ __align__(16) float ws[32 * 128];
    const int tid = threadIdx.x;
    const int row0 = blockIdx.x * 64;
    const int tc = tid & 31;
    const int tr = tid >> 5;
    float acc[8][4];
#pragma unroll
    for (int i = 0; i < 8; ++i)
#pragma unroll
        for (int j = 0; j < 4; ++j) acc[i][j] = 0.f;

    for (int kb = 0; kb < 128; kb += 32) {
        __syncthreads();
#pragma unroll
        for (int i = 0; i < 2; ++i) {
            int f4 = tid + i * 256;
            int r = f4 >> 3;
            int kq = f4 & 7;
            int rr = row0 + r;
            if (rr >= nrows) rr = nrows - 1;
            const float4 v = *reinterpret_cast<const float4*>(&X[rr * 128 + kb + kq * 4]);
            xsT[(kq * 4 + 0) * 72 + r] = v.x;
            xsT[(kq * 4 + 1) * 72 + r] = v.y;
            xsT[(kq * 4 + 2) * 72 + r] = v.z;
            xsT[(kq * 4 + 3) * 72 + r] = v.w;
        }
#pragma unroll
        for (int i = 0; i < 4; ++i) {
            int f4 = tid + i * 256;
            int k = f4 >> 5, c4 = f4 & 31;
            *reinterpret_cast<float4*>(&ws[k * 128 + c4 * 4]) =
                *reinterpret_cast<const float4*>(&W[(kb + k) * 128 + c4 * 4]);
        }
        __syncthreads();
#pragma unroll
        for (int k = 0; k < 32; ++k) {
            const float4 a0 = *reinterpret_cast<const float4*>(&xsT[k * 72 + tr * 8]);
            const float4 a1 = *reinterpret_cast<const float4*>(&xsT[k * 72 + tr * 8 + 4]);
            const float4 bb = *reinterpret_cast<const float4*>(&ws[k * 128 + tc * 4]);
            float av[8] = {a0.x, a0.y, a0.z, a0.w, a1.x, a1.y, a1.z, a1.w};
            float bv[4] = {bb.x, bb.y, bb.z, bb.w};
#pragma unroll
            for (int i = 0; i < 8; ++i)
#pragma unroll
                for (int j = 0; j < 4; ++j)
                    acc[i][j] = fmaf(av[i], bv[j], acc[i][j]);
        }
    }
#pragma unroll
    for (int i = 0; i < 8; ++i) {
        int r = row0 + tr * 8 + i;
        if (r < nrows) {
            float s = dinv[r];
            ushort4 o;
            o.x = f2bf(acc[i][0] * s);
            o.y = f2bf(acc[i][1] * s);
            o.z = f2bf(acc[i][2] * s);
            o.w = f2bf(acc[i][3] * s);
            *reinterpret_cast<ushort4*>(&HS[r * 128 + tc * 4]) = o;
        }
    }
}

// ---------- aggregation: one wave per node ----------
__global__ __launch_bounds__(256) void aggregate_kernel(
    const unsigned int* __restrict__ H,
    const int* __restrict__ rowptr, const int* __restrict__ colidx,
    const float* __restrict__ dinv, const float* __restrict__ bias,
    float* __restrict__ OUT, int n)
{
    int wid = (blockIdx.x * blockDim.x + threadIdx.x) >> 6;
    int lane = threadIdx.x & 63;
    if (wid >= n) return;
    unsigned int self = H[wid * 64 + lane];
    float a0 = bf_lo(self), a1 = bf_hi(self);
    float c0 = 0.f, c1 = 0.f, d0 = 0.f, d1 = 0.f, e0 = 0.f, e1 = 0.f;
    int beg = rowptr[wid], end = rowptr[wid + 1];
    for (int base = beg; base < end; base += 64) {
        int m = end - base; if (m > 64) m = 64;
        int idx = (lane < m) ? colidx[base + lane] : 0;
        int j = 0;
        for (; j + 8 <= m; j += 8) {
            int u0 = __shfl(idx, j + 0);
            int u1 = __shfl(idx, j + 1);
            int u2 = __shfl(idx, j + 2);
            int u3 = __shfl(idx, j + 3);
            int u4 = __shfl(idx, j + 4);
            int u5 = __shfl(idx, j + 5);
            int u6 = __shfl(idx, j + 6);
            int u7 = __shfl(idx, j + 7);
            unsigned int t0 = H[u0 * 64 + lane];
            unsigned int t1 = H[u1 * 64 + lane];
            unsigned int t2 = H[u2 * 64 + lane];
            unsigned int t3 = H[u3 * 64 + lane];
            unsigned int t4 = H[u4 * 64 + lane];
            unsigned int t5 = H[u5 * 64 + lane];
            unsigned int t6 = H[u6 * 64 + lane];
            unsigned int t7 = H[u7 * 64 + lane];
            a0 += bf_lo(t0) + bf_lo(t4);
            a1 += bf_hi(t0) + bf_hi(t4);
            c0 += bf_lo(t1) + bf_lo(t5);
            c1 += bf_hi(t1) + bf_hi(t5);
            d0 += bf_lo(t2) + bf_lo(t6);
            d1 += bf_hi(t2) + bf_hi(t6);
            e0 += bf_lo(t3) + bf_lo(t7);
            e1 += bf_hi(t3) + bf_hi(t7);
        }
        for (; j + 2 <= m; j += 2) {
            int u0 = __shfl(idx, j + 0);
            int u1 = __shfl(idx, j + 1);
            unsigned int t0 = H[u0 * 64 + lane];
            unsigned int t1 = H[u1 * 64 + lane];
            a0 += bf_lo(t0); a1 += bf_hi(t0);
            c0 += bf_lo(t1); c1 += bf_hi(t1);
        }
        if (j < m) {
            int u0 = __shfl(idx, j);
            unsigned int t0 = H[u0 * 64 + lane];
            a0 += bf_lo(t0); a1 += bf_hi(t0);
        }
    }
    a0 += c0 + d0 + e0;
    a1 += c1 + d1 + e1;
    float s = dinv[wid];
    float b0 = bias[lane * 2 + 0];
    float b1 = bias[lane * 2 + 1];
    float2 o;
    o.x = fmaxf(fmaf(a0, s, b0), 0.f);
    o.y = fmaxf(fmaf(a1, s, b1), 0.f);
    *reinterpret_cast<float2*>(&OUT[wid * 128 + lane * 2]) = o;
}

// ---------- global add pool ----------
__global__ __launch_bounds__(128) void pool_kernel(
    const float* __restrict__ H2, const int* __restrict__ batch,
    float* __restrict__ g, int n)
{
    int j = threadIdx.x;
    int n0 = blockIdx.x * 128;
    int n1 = min(n0 + 128, n);
    if (n0 >= n) return;
    float acc = 0.f;
    int cur = batch[n0];
    for (int v = n0; v < n1; ++v) {
        int b = batch[v];
        if (b != cur) {
            atomicAdd(&g[cur * 128 + j], acc);
            acc = 0.f;
            cur = b;
        }
        acc += H2[v * 128 + j];
    }
    atomicAdd(&g[cur * 128 + j], acc);
}

// ---------- fused tail v2: K-split ILP structure ----------
// 256 threads: cg = tid&31 (4 output cols), ks = tid>>5 (K-slice of 8).
// Per layer: each thread does KS independent float4 weight loads into 4 acc
// chains; partials reduced via LDS; LN on threads 0..127.
__global__ __launch_bounds__(256) void tail_kernel(
    const float* __restrict__ g, const int* __restrict__ cell,
    const float* __restrict__ emb,
    const float* __restrict__ Wc, const float* __restrict__ bc,
    const float* __restrict__ lncw, const float* __restrict__ lncb,
    const float* __restrict__ Wf1, const float* __restrict__ bf1,
    const float* __restrict__ ln1w, const float* __restrict__ ln1b,
    const float* __restrict__ Wf2, const float* __restrict__ bf2,
    float* __restrict__ out)
{
    __shared__ __align__(16) float comb[192];
    __shared__ __align__(16) float part[8][132];
    __shared__ float red[128];
    __shared__ __align__(16) float vec[128];
    const int gi = blockIdx.x;
    const int tid = threadIdx.x;
    const int cg = tid & 31;
    const int ks = tid >> 5;

    if (tid < 128) comb[tid] = g[gi * 128 + tid];
    else if (tid < 192) comb[tid] = emb[cell[gi] * 64 + (tid - 128)];
    __syncthreads();

    // ---- layer A: y = comb @ Wc + bc  (K=192, 24 per slice) ----
    {
        float c[24];
#pragma unroll
        for (int i = 0; i < 6; ++i) {
            float4 t = *reinterpret_cast<const float4*>(&comb[ks * 24 + i * 4]);
            c[i * 4 + 0] = t.x; c[i * 4 + 1] = t.y; c[i * 4 + 2] = t.z; c[i * 4 + 3] = t.w;
        }
        float a0 = 0.f, a1 = 0.f, a2 = 0.f, a3 = 0.f;
#pragma unroll
        for (int i = 0; i < 24; ++i) {
            const float4 w = *reinterpret_cast<const float4*>(&Wc[(ks * 24 + i) * 128 + cg * 4]);
            a0 = fmaf(c[i], w.x, a0);
            a1 = fmaf(c[i], w.y, a1);
            a2 = fmaf(c[i], w.z, a2);
            a3 = fmaf(c[i], w.w, a3);
        }
        float4 o; o.x = a0; o.y = a1; o.z = a2; o.w = a3;
        *reinterpret_cast<float4*>(&part[ks][cg * 4]) = o;
    }
    __syncthreads();
    // reduce + LN + relu -> vec
    {
        float y = 0.f;
        if (tid < 128) {
            y = bc[tid];
#pragma unroll
            for (int s = 0; s < 8; ++s) y += part[s][tid];
            red[tid] = y;
        }
        __syncthreads();
        for (int off = 64; off > 0; off >>= 1) {
            if (tid < off) red[tid] += red[tid + off];
            __syncthreads();
        }
        float mu = red[0] * (1.f / 128.f);
        __syncthreads();
        float d = (tid < 128) ? (y - mu) : 0.f;
        if (tid < 128) red[tid] = d * d;
        __syncthreads();
        for (int off = 64; off > 0; off >>= 1) {
            if (tid < off) red[tid] += red[tid + off];
            __syncthreads();
        }
        float var = red[0] * (1.f / 128.f);
        __syncthreads();
        if (tid < 128) {
            float yv = d * rsqrtf(var + EPS) * lncw[tid] + lncb[tid];
            vec[tid] = fmaxf(yv, 0.f);
        }
    }
    __syncthreads();

    // ---- layer B: z = relu(vec @ Wf1 + bf1), then LN ----
    {
        float c[16];
#pragma unroll
        for (int i = 0; i < 4; ++i) {
            float4 t = *reinterpret_cast<const float4*>(&vec[ks * 16 + i * 4]);
            c[i * 4 + 0] = t.x; c[i * 4 + 1] = t.y; c[i * 4 + 2] = t.z; c[i * 4 + 3] = t.w;
        }
        float a0 = 0.f, a1 = 0.f, a2 = 0.f, a3 = 0.f;
#pragma unroll
        for (int i = 0; i < 16; ++i) {
            const float4 w = *reinterpret_cast<const float4*>(&Wf1[(ks * 16 + i) * 128 + cg * 4]);
            a0 = fmaf(c[i], w.x, a0);
            a1 = fmaf(c[i], w.y, a1);
            a2 = fmaf(c[i], w.z, a2);
            a3 = fmaf(c[i], w.w, a3);
        }
        float4 o; o.x = a0; o.y = a1; o.z = a2; o.w = a3;
        *reinterpret_cast<float4*>(&part[ks][cg * 4]) = o;
    }
    __syncthreads();
    {
        float y = 0.f;
        if (tid < 128) {
            y = bf1[tid];
#pragma unroll
            for (int s = 0; s < 8; ++s) y += part[s][tid];
            y = fmaxf(y, 0.f);            // relu BEFORE the LN
            red[tid] = y;
        }
        __syncthreads();
        for (int off = 64; off > 0; off >>= 1) {
            if (tid < off) red[tid] += red[tid + off];
            __syncthreads();
        }
        float mu = red[0] * (1.f / 128.f);
        __syncthreads();
        float d = (tid < 128) ? (y - mu) : 0.f;
        if (tid < 128) red[tid] = d * d;
        __syncthreads();
        for (int off = 64; off > 0; off >>= 1) {
            if (tid < off) red[tid] += red[tid + off];
            __syncthreads();
        }
        float var = red[0] * (1.f / 128.f);
        __syncthreads();
        if (tid < 128) {
            vec[tid] = d * rsqrtf(var + EPS) * ln1w[tid] + ln1b[tid];   // no relu
        }
    }
    __syncthreads();

    // ---- layer C: out = vec @ Wf2 + bf2 ----
    {
        float c[16];
#pragma unroll
        for (int i = 0; i < 4; ++i) {
            float4 t = *reinterpret_cast<const float4*>(&vec[ks * 16 + i * 4]);
            c[i * 4 + 0] = t.x; c[i * 4 + 1] = t.y; c[i * 4 + 2] = t.z; c[i * 4 + 3] = t.w;
        }
        float a0 = 0.f, a1 = 0.f, a2 = 0.f, a3 = 0.f;
#pragma unroll
        for (int i = 0; i < 16; ++i) {
            const float4 w = *reinterpret_cast<const float4*>(&Wf2[(ks * 16 + i) * 128 + cg * 4]);
            a0 = fmaf(c[i], w.x, a0);
            a1 = fmaf(c[i], w.y, a1);
            a2 = fmaf(c[i], w.z, a2);
            a3 = fmaf(c[i], w.w, a3);
        }
        float4 o; o.x = a0; o.y = a1; o.z = a2; o.w = a3;
        *reinterpret_cast<float4*>(&part[ks][cg * 4]) = o;
    }
    __syncthreads();
    if (tid < 128) {
        float y = bf2[tid];
#pragma unroll
        for (int s = 0; s < 8; ++s) y += part[s][tid];
        out[gi * 128 + tid] = y;
    }
}

// ---------- host launch ----------
extern "C" void kernel_launch(void* const* d_in, const int* in_sizes, int n_in,
                              void* d_out, int out_size, void* d_ws, size_t ws_size,
                              hipStream_t stream) {
    const float* x    = (const float*)d_in[0];
    const int*   ei   = (const int*)d_in[1];
    const int*   batch= (const int*)d_in[2];
    const int*   cell = (const int*)d_in[3];
    const float* W1   = (const float*)d_in[4];
    const float* b1   = (const float*)d_in[5];
    const float* W2   = (const float*)d_in[6];
    const float* b2   = (const float*)d_in[7];
    const float* emb  = (const float*)d_in[8];
    const float* Wc   = (const float*)d_in[9];
    const float* bc   = (const float*)d_in[10];
    const float* lncw = (const float*)d_in[11];
    const float* lncb = (const float*)d_in[12];
    const float* Wf1  = (const float*)d_in[13];
    const float* bf1  = (const float*)d_in[14];
    const float* ln1w = (const float*)d_in[15];
    const float* ln1b = (const float*)d_in[16];
    const float* Wf2  = (const float*)d_in[17];
    const float* bf2  = (const float*)d_in[18];
    float* out = (float*)d_out;

    char* ws = (char*)d_ws;
    size_t off = 0;
    auto alloc = [&](size_t bytes) { char* p = ws + off; off = (off + bytes + 255) & ~size_t(255); return p; };
    float* dinv       = (float*)alloc(N_NODES * 4);
    int*   rowptr     = (int*)  alloc((N_NODES + 1) * 4);
    int*   colidx     = (int*)  alloc(NEDGE * 4);
    int*   bucketCnt  = (int*)  alloc(NBUCK * 4);
    int*   bucketBase = (int*)  alloc((NBUCK + 1) * 4);
    int*   bucketCursor=(int*)  alloc(NBUCK * 4);
    uint2* recbuf     = (uint2*)alloc((size_t)NEDGE * 8);
    unsigned short* hs = (unsigned short*)alloc((size_t)N_NODES * 128 * 2);
    float* nodebuf    = (float*)alloc((size_t)N_NODES * 128 * 4);
    float* g          = (float*)alloc((size_t)NGRAPH * 128 * 4);

    const int nbEdge = (NEDGE + EPB - 1) / EPB;        // 196
    const int nbGemm = (N_NODES + 63) / 64;            // 782
    const int nbAgg  = (N_NODES + 3) / 4;              // 12500
    const int nbPool = (N_NODES + 127) / 128;          // 391

    hipMemsetAsync(bucketCnt, 0, NBUCK * 4, stream);
    hipMemsetAsync(g, 0, (size_t)NGRAPH * 128 * 4, stream);

    // CSR build
    bucket_hist_kernel<<<nbEdge, 256, 0, stream>>>(ei, bucketCnt, NEDGE);
    bucket_scan_kernel<<<1, 256, 0, stream>>>(bucketCnt, bucketBase, bucketCursor, rowptr);
    bucket_scatter_kernel<<<nbEdge, 256, 0, stream>>>(ei, bucketCursor, recbuf, NEDGE);
    bucket_csr_kernel<<<NBUCK, 256, 0, stream>>>(recbuf, bucketBase, rowptr, dinv, colidx);

    // conv1
    gemm_scale_kernel<<<nbGemm, 256, 0, stream>>>(x, W1, dinv, hs, N_NODES);
    aggregate_kernel<<<nbAgg, 256, 0, stream>>>((const unsigned int*)hs, rowptr, colidx,
                                                dinv, b1, nodebuf, N_NODES);
    // conv2
    gemm_scale_kernel<<<nbGemm, 256, 0, stream>>>(nodebuf, W2, dinv, hs, N_NODES);
    aggregate_kernel<<<nbAgg, 256, 0, stream>>>((const unsigned int*)hs, rowptr, colidx,
                                                dinv, b2, nodebuf, N_NODES);
    // pool + tail
    pool_kernel<<<nbPool, 128, 0, stream>>>(nodebuf, batch, g, N_NODES);
    tail_kernel<<<NGRAPH, 256, 0, stream>>>(g, cell, emb, Wc, bc, lncw, lncb,
                                            Wf1, bf1, ln1w, ln1b, Wf2, bf2, out);
}

// Round 5
// 275.232 us; speedup vs baseline: 1.7693x; 1.1409x over previous
//
#include <hip/hip_runtime.h>

#define N_NODES 50000
#define NFEAT 128
#define NEDGE 800000
#define NGRAPH 512
#define NCE 64
#define EPS 1e-5f
#define NBUCK 196            // ceil(50000/256) buckets of 256 nodes
#define EPB 4096             // edges per bucket_scatter block
#define CSR_STAGE_CAP 8192   // LDS staging entries in bucket_csr

typedef short s8v __attribute__((ext_vector_type(8)));
typedef float f4v __attribute__((ext_vector_type(4)));

// ---------- bf16 helpers (manual, bit-exact RNE) ----------
static __device__ __forceinline__ unsigned short f2bf(float f) {
    unsigned int u = __float_as_uint(f);
    unsigned int r = u + 0x7fffu + ((u >> 16) & 1u);
    return (unsigned short)(r >> 16);
}
static __device__ __forceinline__ float bf_lo(unsigned int packed) {
    return __uint_as_float(packed << 16);
}
static __device__ __forceinline__ float bf_hi(unsigned int packed) {
    return __uint_as_float(packed & 0xffff0000u);
}

// ---------- 1. bucket histogram ----------
__global__ __launch_bounds__(256) void bucket_hist_kernel(
    const int* __restrict__ ei, int* __restrict__ bucketCnt, int E)
{
    __shared__ int hist[NBUCK];
    int tid = threadIdx.x;
    if (tid < NBUCK) hist[tid] = 0;
    __syncthreads();
    int e0 = blockIdx.x * EPB + tid;
#pragma unroll
    for (int i = 0; i < EPB / 256; ++i) {
        int e = e0 + i * 256;
        if (e < E) atomicAdd(&hist[ei[E + e] >> 8], 1);
    }
    __syncthreads();
    if (tid < NBUCK && hist[tid] > 0) atomicAdd(&bucketCnt[tid], hist[tid]);
}

// ---------- 2. scan bucket counts ----------
__global__ __launch_bounds__(256) void bucket_scan_kernel(
    const int* __restrict__ bucketCnt, int* __restrict__ bucketBase,
    int* __restrict__ bucketCursor, int* __restrict__ rowptr)
{
    __shared__ int s[256];
    int tid = threadIdx.x;
    int v = (tid < NBUCK) ? bucketCnt[tid] : 0;
    s[tid] = v; __syncthreads();
    for (int off = 1; off < 256; off <<= 1) {
        int t = (tid >= off) ? s[tid - off] : 0;
        __syncthreads();
        s[tid] += t;
        __syncthreads();
    }
    int excl = s[tid] - v;
    if (tid <= NBUCK) bucketBase[tid] = excl;
    if (tid < NBUCK) bucketCursor[tid] = excl;
    if (tid == NBUCK) rowptr[N_NODES] = excl;   // == E
}

// ---------- 3. bucket scatter: packed uint records (src | dst<<16) ----------
__global__ __launch_bounds__(256) void bucket_scatter_kernel(
    const int* __restrict__ ei, int* __restrict__ bucketCursor,
    unsigned int* __restrict__ recbuf, int E)
{
    __shared__ int hist[NBUCK];
    __shared__ int lbase[NBUCK];
    __shared__ int gbase[NBUCK];
    __shared__ int cur[NBUCK];
    __shared__ int scanbuf[256];
    __shared__ unsigned int staging[EPB];
    int tid = threadIdx.x;
    if (tid < NBUCK) { hist[tid] = 0; cur[tid] = 0; }
    __syncthreads();

    unsigned int rec[EPB / 256];
    int e0 = blockIdx.x * EPB + tid;
#pragma unroll
    for (int i = 0; i < EPB / 256; ++i) {
        int e = e0 + i * 256;
        if (e < E) {
            unsigned int sv = (unsigned)ei[e];
            unsigned int dv = (unsigned)ei[E + e];
            rec[i] = sv | (dv << 16);
            atomicAdd(&hist[dv >> 8], 1);
        } else {
            rec[i] = 0xffffffffu;
        }
    }
    __syncthreads();
    int v = (tid < NBUCK) ? hist[tid] : 0;
    scanbuf[tid] = v; __syncthreads();
    for (int off = 1; off < 256; off <<= 1) {
        int t = (tid >= off) ? scanbuf[tid - off] : 0;
        __syncthreads();
        scanbuf[tid] += t;
        __syncthreads();
    }
    if (tid < NBUCK) lbase[tid] = scanbuf[tid] - v;
    int total = scanbuf[255];
    if (tid < NBUCK) gbase[tid] = (v > 0) ? atomicAdd(&bucketCursor[tid], v) : 0;
    __syncthreads();
#pragma unroll
    for (int i = 0; i < EPB / 256; ++i) {
        if (rec[i] != 0xffffffffu) {
            int b = rec[i] >> 24;       // dst >> 8
            int loc = atomicAdd(&cur[b], 1);
            staging[lbase[b] + loc] = rec[i];
        }
    }
    __syncthreads();
    for (int s = tid; s < total; s += 256) {
        unsigned int r = staging[s];
        int b = r >> 24;
        recbuf[gbase[b] + (s - lbase[b])] = r;
    }
}

// ---------- 4. per-bucket CSR finalize: ushort colidx ----------
__global__ __launch_bounds__(256) void bucket_csr_kernel(
    const unsigned int* __restrict__ recbuf, const int* __restrict__ bucketBase,
    int* __restrict__ rowptr, float* __restrict__ dinv,
    unsigned short* __restrict__ colidx)
{
    __shared__ int cnt[256];
    __shared__ int cur[256];
    __shared__ int scanbuf[256];
    __shared__ int stage[CSR_STAGE_CAP];
    int b = blockIdx.x, tid = threadIdx.x;
    int base = bucketBase[b];
    int len = bucketBase[b + 1] - base;
    cnt[tid] = 0;
    __syncthreads();
    for (int s = tid; s < len; s += 256) {
        unsigned int r = recbuf[base + s];
        atomicAdd(&cnt[(r >> 16) & 255], 1);
    }
    __syncthreads();
    int v = cnt[tid];
    scanbuf[tid] = v; __syncthreads();
    for (int off = 1; off < 256; off <<= 1) {
        int t = (tid >= off) ? scanbuf[tid - off] : 0;
        __syncthreads();
        scanbuf[tid] += t;
        __syncthreads();
    }
    int excl = scanbuf[tid] - v;
    int node = b * 256 + tid;
    if (node < N_NODES) {
        rowptr[node] = base + excl;
        dinv[node] = rsqrtf((float)v + 1.0f);
    }
    cur[tid] = excl;
    __syncthreads();
    for (int s = tid; s < len; s += 256) {
        unsigned int r = recbuf[base + s];
        int pos = atomicAdd(&cur[(r >> 16) & 255], 1);
        if (pos < CSR_STAGE_CAP) stage[pos] = (int)(r & 0xffffu);
        else colidx[base + pos] = (unsigned short)(r & 0xffffu);
    }
    __syncthreads();
    int m = (len < CSR_STAGE_CAP) ? len : CSR_STAGE_CAP;
    for (int s = tid; s < m; s += 256) colidx[base + s] = (unsigned short)stage[s];
}

// ---------- weight cast+transpose: WT[n][k] = bf16(W[k][n]) for W1 and W2 ----------
__global__ __launch_bounds__(256) void wcast_kernel(
    const float* __restrict__ W1, const float* __restrict__ W2,
    unsigned short* __restrict__ WT1, unsigned short* __restrict__ WT2)
{
    const float* W = blockIdx.y ? W2 : W1;
    unsigned short* WT = blockIdx.y ? WT2 : WT1;
    int idx = blockIdx.x * 256 + threadIdx.x;   // 64 blocks x 256 = 16384
    int k = idx >> 7, n = idx & 127;
    WT[n * 128 + k] = f2bf(W[idx]);
}

// ---------- MFMA GEMM: HS[r][c] = bf16( (A @ W)[r][c] * dinv[r] ) ----------
// block 256 = 4 waves; tile 128 rows x 128 cols; wave = 32 rows x 128 cols.
// A: m=lane&15, k=quad*8+j (m120-verified); B from WT[n][k]: n=lane&15 (m97 gemm_bt);
// D: col=lane&15, row=quad*4+reg (m89/m91-verified).
template<bool FP32IN>
__global__ __launch_bounds__(256) void gemm_mfma_kernel(
    const void* __restrict__ Ain, const unsigned short* __restrict__ WTg,
    const float* __restrict__ dinv, unsigned short* __restrict__ HS, int nrows)
{
    __shared__ unsigned short as[128 * 128];   // 32 KB; reused for result staging
    __shared__ unsigned short wt[128 * 128];   // 32 KB
    const int tid = threadIdx.x;
    const int row0 = blockIdx.x * 128;

    // stage WT (bf16, already [n][k])
    {
        const uint4* src = reinterpret_cast<const uint4*>(WTg);
        uint4* dst = reinterpret_cast<uint4*>(wt);
#pragma unroll
        for (int i = 0; i < 8; ++i) dst[tid + i * 256] = src[tid + i * 256];
    }
    // stage A tile (cast if fp32 input)
    if (FP32IN) {
        const float* X = (const float*)Ain;
#pragma unroll
        for (int i = 0; i < 16; ++i) {
            int f = tid + i * 256;
            int r = f >> 5, c4 = f & 31;
            int rr = row0 + r; if (rr >= nrows) rr = nrows - 1;
            float4 v = *reinterpret_cast<const float4*>(&X[rr * 128 + c4 * 4]);
            ushort4 o;
            o.x = f2bf(v.x); o.y = f2bf(v.y); o.z = f2bf(v.z); o.w = f2bf(v.w);
            *reinterpret_cast<ushort4*>(&as[r * 128 + c4 * 4]) = o;
        }
    } else {
        const unsigned short* X = (const unsigned short*)Ain;
#pragma unroll
        for (int i = 0; i < 8; ++i) {
            int f = tid + i * 256;
            int r = f >> 4, c8 = f & 15;
            int rr = row0 + r; if (rr >= nrows) rr = nrows - 1;
            *reinterpret_cast<uint4*>(&as[r * 128 + c8 * 8]) =
                *reinterpret_cast<const uint4*>(&X[rr * 128 + c8 * 8]);
        }
    }
    __syncthreads();

    const int w = tid >> 6;
    const int lane = tid & 63;
    const int quad = lane >> 4;
    const int col0 = lane & 15;

    // preload A fragments (this wave's 32 rows)
    s8v afr[2][4];
#pragma unroll
    for (int rt = 0; rt < 2; ++rt)
#pragma unroll
        for (int kt = 0; kt < 4; ++kt)
            afr[rt][kt] = *reinterpret_cast<const s8v*>(
                &as[(w * 32 + rt * 16 + col0) * 128 + kt * 32 + quad * 8]);

    f4v acc[2][8];
#pragma unroll
    for (int rt = 0; rt < 2; ++rt)
#pragma unroll
        for (int nt = 0; nt < 8; ++nt)
            acc[rt][nt] = (f4v){0.f, 0.f, 0.f, 0.f};

#pragma unroll
    for (int nt = 0; nt < 8; ++nt) {
        s8v bfr[4];
#pragma unroll
        for (int kt = 0; kt < 4; ++kt)
            bfr[kt] = *reinterpret_cast<const s8v*>(
                &wt[(nt * 16 + col0) * 128 + kt * 32 + quad * 8]);
#pragma unroll
        for (int rt = 0; rt < 2; ++rt)
#pragma unroll
            for (int kt = 0; kt < 4; ++kt)
                acc[rt][nt] = __builtin_amdgcn_mfma_f32_16x16x32_bf16(
                    afr[rt][kt], bfr[kt], acc[rt][nt], 0, 0, 0);
    }

    // dinv per (rt, reg) row
    float dv[2][4];
#pragma unroll
    for (int rt = 0; rt < 2; ++rt)
#pragma unroll
        for (int reg = 0; reg < 4; ++reg) {
            int r = row0 + w * 32 + rt * 16 + quad * 4 + reg;
            dv[rt][reg] = (r < nrows) ? dinv[r] : 0.f;
        }

    // results -> own region of `as` (bf16), then coalesced copy-out
#pragma unroll
    for (int rt = 0; rt < 2; ++rt)
#pragma unroll
        for (int nt = 0; nt < 8; ++nt)
#pragma unroll
            for (int reg = 0; reg < 4; ++reg) {
                int rl = w * 32 + rt * 16 + quad * 4 + reg;
                as[rl * 128 + nt * 16 + col0] = f2bf(acc[rt][nt][reg] * dv[rt][reg]);
            }
    __syncthreads();
#pragma unroll
    for (int i = 0; i < 8; ++i) {
        int f = tid + i * 256;
        int r = f >> 4, c8 = f & 15;
        if (row0 + r < nrows)
            *reinterpret_cast<uint4*>(&HS[(size_t)(row0 + r) * 128 + c8 * 8]) =
                *reinterpret_cast<const uint4*>(&as[r * 128 + c8 * 8]);
    }
}

// ---------- aggregation: one wave per node; OUTMODE 0=f32, 1=bf16 ----------
template<int OUTMODE>
__global__ __launch_bounds__(256) void aggregate_kernel(
    const unsigned int* __restrict__ H,
    const int* __restrict__ rowptr, const unsigned short* __restrict__ colidx,
    const float* __restrict__ dinv, const float* __restrict__ bias,
    void* __restrict__ OUTv, int n)
{
    int wid = (blockIdx.x * blockDim.x + threadIdx.x) >> 6;
    int lane = threadIdx.x & 63;
    if (wid >= n) return;
    unsigned int self = H[wid * 64 + lane];
    float a0 = bf_lo(self), a1 = bf_hi(self);
    float c0 = 0.f, c1 = 0.f, d0 = 0.f, d1 = 0.f, e0 = 0.f, e1 = 0.f;
    int beg = rowptr[wid], end = rowptr[wid + 1];
    for (int base = beg; base < end; base += 64) {
        int m = end - base; if (m > 64) m = 64;
        int idx = (lane < m) ? (int)colidx[base + lane] : 0;
        int j = 0;
        for (; j + 8 <= m; j += 8) {
            int u0 = __shfl(idx, j + 0);
            int u1 = __shfl(idx, j + 1);
            int u2 = __shfl(idx, j + 2);
            int u3 = __shfl(idx, j + 3);
            int u4 = __shfl(idx, j + 4);
            int u5 = __shfl(idx, j + 5);
            int u6 = __shfl(idx, j + 6);
            int u7 = __shfl(idx, j + 7);
            unsigned int t0 = H[u0 * 64 + lane];
            unsigned int t1 = H[u1 * 64 + lane];
            unsigned int t2 = H[u2 * 64 + lane];
            unsigned int t3 = H[u3 * 64 + lane];
            unsigned int t4 = H[u4 * 64 + lane];
            unsigned int t5 = H[u5 * 64 + lane];
            unsigned int t6 = H[u6 * 64 + lane];
            unsigned int t7 = H[u7 * 64 + lane];
            a0 += bf_lo(t0) + bf_lo(t4);
            a1 += bf_hi(t0) + bf_hi(t4);
            c0 += bf_lo(t1) + bf_lo(t5);
            c1 += bf_hi(t1) + bf_hi(t5);
            d0 += bf_lo(t2) + bf_lo(t6);
            d1 += bf_hi(t2) + bf_hi(t6);
            e0 += bf_lo(t3) + bf_lo(t7);
            e1 += bf_hi(t3) + bf_hi(t7);
        }
        for (; j + 2 <= m; j += 2) {
            int u0 = __shfl(idx, j + 0);
            int u1 = __shfl(idx, j + 1);
            unsigned int t0 = H[u0 * 64 + lane];
            unsigned int t1 = H[u1 * 64 + lane];
            a0 += bf_lo(t0); a1 += bf_hi(t0);
            c0 += bf_lo(t1); c1 += bf_hi(t1);
        }
        if (j < m) {
            int u0 = __shfl(idx, j);
            unsigned int t0 = H[u0 * 64 + lane];
            a0 += bf_lo(t0); a1 += bf_hi(t0);
        }
    }
    a0 += c0 + d0 + e0;
    a1 += c1 + d1 + e1;
    float s = dinv[wid];
    float b0 = bias[lane * 2 + 0];
    float b1 = bias[lane * 2 + 1];
    float o0 = fmaxf(fmaf(a0, s, b0), 0.f);
    float o1 = fmaxf(fmaf(a1, s, b1), 0.f);
    if (OUTMODE == 1) {
        unsigned int* OUT = (unsigned int*)OUTv;
        OUT[wid * 64 + lane] = (unsigned int)f2bf(o0) | ((unsigned int)f2bf(o1) << 16);
    } else {
        float2* OUT = (float2*)OUTv;
        float2 o; o.x = o0; o.y = o1;
        OUT[wid * 64 + lane] = o;
    }
}

// ---------- global add pool ----------
__global__ __launch_bounds__(128) void pool_kernel(
    const float* __restrict__ H2, const int* __restrict__ batch,
    float* __restrict__ g, int n)
{
    int j = threadIdx.x;
    int n0 = blockIdx.x * 128;
    int n1 = min(n0 + 128, n);
    if (n0 >= n) return;
    float acc = 0.f;
    int cur = batch[n0];
    for (int v = n0; v < n1; ++v) {
        int b = batch[v];
        if (b != cur) {
            atomicAdd(&g[cur * 128 + j], acc);
            acc = 0.f;
            cur = b;
        }
        acc += H2[v * 128 + j];
    }
    atomicAdd(&g[cur * 128 + j], acc);
}

// ---------- fused tail v3: K-split ILP + single-pass shfl LN ----------
__global__ __launch_bounds__(256) void tail_kernel(
    const float* __restrict__ g, const int* __restrict__ cell,
    const float* __restrict__ emb,
    const float* __restrict__ Wc, const float* __restrict__ bc,
    const float* __restrict__ lncw, const float* __restrict__ lncb,
    const float* __restrict__ Wf1, const float* __restrict__ bf1,
    const float* __restrict__ ln1w, const float* __restrict__ ln1b,
    const float* __restrict__ Wf2, const float* __restrict__ bf2,
    float* __restrict__ out)
{
    __shared__ __align__(16) float comb[192];
    __shared__ __align__(16) float part[8][132];
    __shared__ float red[4];
    __shared__ __align__(16) float vec[128];
    const int gi = blockIdx.x;
    const int tid = threadIdx.x;
    const int cg = tid & 31;
    const int ks = tid >> 5;

    if (tid < 128) comb[tid] = g[gi * 128 + tid];
    else if (tid < 192) comb[tid] = emb[cell[gi] * 64 + (tid - 128)];
    __syncthreads();

    // ---- layer A: comb @ Wc ----
    {
        float c[24];
#pragma unroll
        for (int i = 0; i < 6; ++i) {
            float4 t = *reinterpret_cast<const float4*>(&comb[ks * 24 + i * 4]);
            c[i * 4 + 0] = t.x; c[i * 4 + 1] = t.y; c[i * 4 + 2] = t.z; c[i * 4 + 3] = t.w;
        }
        float a0 = 0.f, a1 = 0.f, a2 = 0.f, a3 = 0.f;
#pragma unroll
        for (int i = 0; i < 24; ++i) {
            const float4 w = *reinterpret_cast<const float4*>(&Wc[(ks * 24 + i) * 128 + cg * 4]);
            a0 = fmaf(c[i], w.x, a0);
            a1 = fmaf(c[i], w.y, a1);
            a2 = fmaf(c[i], w.z, a2);
            a3 = fmaf(c[i], w.w, a3);
        }
        float4 o; o.x = a0; o.y = a1; o.z = a2; o.w = a3;
        *reinterpret_cast<float4*>(&part[ks][cg * 4]) = o;
    }
    __syncthreads();
    {
        float y = 0.f;
        if (tid < 128) {
            y = bc[tid];
#pragma unroll
            for (int s = 0; s < 8; ++s) y += part[s][tid];
        }
        float s1 = (tid < 128) ? y : 0.f;
        float s2 = (tid < 128) ? y * y : 0.f;
        if (tid < 128) {
#pragma unroll
            for (int off = 32; off > 0; off >>= 1) {
                s1 += __shfl_down(s1, off);
                s2 += __shfl_down(s2, off);
            }
            if ((tid & 63) == 0) { red[(tid >> 6) * 2] = s1; red[(tid >> 6) * 2 + 1] = s2; }
        }
        __syncthreads();
        float mu = (red[0] + red[2]) * (1.f / 128.f);
        float ms = (red[1] + red[3]) * (1.f / 128.f);
        float var = ms - mu * mu;
        if (tid < 128) {
            float yv = (y - mu) * rsqrtf(var + EPS) * lncw[tid] + lncb[tid];
            vec[tid] = fmaxf(yv, 0.f);
        }
    }
    __syncthreads();

    // ---- layer B: vec @ Wf1, relu, LN ----
    {
        float c[16];
#pragma unroll
        for (int i = 0; i < 4; ++i) {
            float4 t = *reinterpret_cast<const float4*>(&vec[ks * 16 + i * 4]);
            c[i * 4 + 0] = t.x; c[i * 4 + 1] = t.y; c[i * 4 + 2] = t.z; c[i * 4 + 3] = t.w;
        }
        float a0 = 0.f, a1 = 0.f, a2 = 0.f, a3 = 0.f;
#pragma unroll
        for (int i = 0; i < 16; ++i) {
            const float4 w = *reinterpret_cast<const float4*>(&Wf1[(ks * 16 + i) * 128 + cg * 4]);
            a0 = fmaf(c[i], w.x, a0);
            a1 = fmaf(c[i], w.y, a1);
            a2 = fmaf(c[i], w.z, a2);
            a3 = fmaf(c[i], w.w, a3);
        }
        float4 o; o.x = a0; o.y = a1; o.z = a2; o.w = a3;
        *reinterpret_cast<float4*>(&part[ks][cg * 4]) = o;
    }
    __syncthreads();
    {
        float y = 0.f;
        if (tid < 128) {
            y = bf1[tid];
#pragma unroll
            for (int s = 0; s < 8; ++s) y += part[s][tid];
            y = fmaxf(y, 0.f);                 // relu BEFORE LN
        }
        float s1 = (tid < 128) ? y : 0.f;
        float s2 = (tid < 128) ? y * y : 0.f;
        if (tid < 128) {
#pragma unroll
            for (int off = 32; off > 0; off >>= 1) {
                s1 += __shfl_down(s1, off);
                s2 += __shfl_down(s2, off);
            }
            if ((tid & 63) == 0) { red[(tid >> 6) * 2] = s1; red[(tid >> 6) * 2 + 1] = s2; }
        }
        __syncthreads();
        float mu = (red[0] + red[2]) * (1.f / 128.f);
        float ms = (red[1] + red[3]) * (1.f / 128.f);
        float var = ms - mu * mu;
        if (tid < 128)
            vec[tid] = (y - mu) * rsqrtf(var + EPS) * ln1w[tid] + ln1b[tid];   // no relu
    }
    __syncthreads();

    // ---- layer C: vec @ Wf2 ----
    {
        float c[16];
#pragma unroll
        for (int i = 0; i < 4; ++i) {
            float4 t = *reinterpret_cast<const float4*>(&vec[ks * 16 + i * 4]);
            c[i * 4 + 0] = t.x; c[i * 4 + 1] = t.y; c[i * 4 + 2] = t.z; c[i * 4 + 3] = t.w;
        }
        float a0 = 0.f, a1 = 0.f, a2 = 0.f, a3 = 0.f;
#pragma unroll
        for (int i = 0; i < 16; ++i) {
            const float4 w = *reinterpret_cast<const float4*>(&Wf2[(ks * 16 + i) * 128 + cg * 4]);
            a0 = fmaf(c[i], w.x, a0);
            a1 = fmaf(c[i], w.y, a1);
            a2 = fmaf(c[i], w.z, a2);
            a3 = fmaf(c[i], w.w, a3);
        }
        float4 o; o.x = a0; o.y = a1; o.z = a2; o.w = a3;
        *reinterpret_cast<float4*>(&part[ks][cg * 4]) = o;
    }
    __syncthreads();
    if (tid < 128) {
        float y = bf2[tid];
#pragma unroll
        for (int s = 0; s < 8; ++s) y += part[s][tid];
        out[gi * 128 + tid] = y;
    }
}

// ---------- host launch ----------
extern "C" void kernel_launch(void* const* d_in, const int* in_sizes, int n_in,
                              void* d_out, int out_size, void* d_ws, size_t ws_size,
                              hipStream_t stream) {
    const float* x    = (const float*)d_in[0];
    const int*   ei   = (const int*)d_in[1];
    const int*   batch= (const int*)d_in[2];
    const int*   cell = (const int*)d_in[3];
    const float* W1   = (const float*)d_in[4];
    const float* b1   = (const float*)d_in[5];
    const float* W2   = (const float*)d_in[6];
    const float* b2   = (const float*)d_in[7];
    const float* emb  = (const float*)d_in[8];
    const float* Wc   = (const float*)d_in[9];
    const float* bc   = (const float*)d_in[10];
    const float* lncw = (const float*)d_in[11];
    const float* lncb = (const float*)d_in[12];
    const float* Wf1  = (const float*)d_in[13];
    const float* bf1  = (const float*)d_in[14];
    const float* ln1w = (const float*)d_in[15];
    const float* ln1b = (const float*)d_in[16];
    const float* Wf2  = (const float*)d_in[17];
    const float* bf2  = (const float*)d_in[18];
    float* out = (float*)d_out;

    char* ws = (char*)d_ws;
    size_t off = 0;
    auto alloc = [&](size_t bytes) { char* p = ws + off; off = (off + bytes + 255) & ~size_t(255); return p; };
    float*          dinv        = (float*)alloc(N_NODES * 4);
    int*            rowptr      = (int*)  alloc((N_NODES + 1) * 4);
    unsigned short* colidx      = (unsigned short*)alloc((size_t)NEDGE * 2);
    int*            bucketCnt   = (int*)  alloc(NBUCK * 4);
    int*            bucketBase  = (int*)  alloc((NBUCK + 1) * 4);
    int*            bucketCursor= (int*)  alloc(NBUCK * 4);
    unsigned int*   recbuf      = (unsigned int*)alloc((size_t)NEDGE * 4);
    unsigned short* wt1         = (unsigned short*)alloc(128 * 128 * 2);
    unsigned short* wt2         = (unsigned short*)alloc(128 * 128 * 2);
    unsigned short* hs          = (unsigned short*)alloc((size_t)N_NODES * 128 * 2);
    unsigned short* h1          = (unsigned short*)alloc((size_t)N_NODES * 128 * 2);
    float*          nodebuf     = (float*)alloc((size_t)N_NODES * 128 * 4);
    float*          g           = (float*)alloc((size_t)NGRAPH * 128 * 4);

    const int nbEdge = (NEDGE + EPB - 1) / EPB;        // 196
    const int nbGemm = (N_NODES + 127) / 128;          // 391
    const int nbAgg  = (N_NODES + 3) / 4;              // 12500
    const int nbPool = (N_NODES + 127) / 128;          // 391

    hipMemsetAsync(bucketCnt, 0, NBUCK * 4, stream);
    hipMemsetAsync(g, 0, (size_t)NGRAPH * 128 * 4, stream);

    // weight cast (independent of everything else)
    wcast_kernel<<<dim3(64, 2), 256, 0, stream>>>(W1, W2, wt1, wt2);

    // CSR build
    bucket_hist_kernel<<<nbEdge, 256, 0, stream>>>(ei, bucketCnt, NEDGE);
    bucket_scan_kernel<<<1, 256, 0, stream>>>(bucketCnt, bucketBase, bucketCursor, rowptr);
    bucket_scatter_kernel<<<nbEdge, 256, 0, stream>>>(ei, bucketCursor, recbuf, NEDGE);
    bucket_csr_kernel<<<NBUCK, 256, 0, stream>>>(recbuf, bucketBase, rowptr, dinv, colidx);

    // conv1: gemm (fp32 in) -> aggregate (bf16 out)
    gemm_mfma_kernel<true><<<nbGemm, 256, 0, stream>>>(x, wt1, dinv, hs, N_NODES);
    aggregate_kernel<1><<<nbAgg, 256, 0, stream>>>((const unsigned int*)hs, rowptr, colidx,
                                                   dinv, b1, h1, N_NODES);
    // conv2: gemm (bf16 in) -> aggregate (f32 out)
    gemm_mfma_kernel<false><<<nbGemm, 256, 0, stream>>>(h1, wt2, dinv, hs, N_NODES);
    aggregate_kernel<0><<<nbAgg, 256, 0, stream>>>((const unsigned int*)hs, rowptr, colidx,
                                                   dinv, b2, nodebuf, N_NODES);
    // pool + tail
    pool_kernel<<<nbPool, 128, 0, stream>>>(nodebuf, batch, g, N_NODES);
    tail_kernel<<<NGRAPH, 256, 0, stream>>>(g, cell, emb, Wc, bc, lncw, lncb,
                                            Wf1, bf1, ln1w, ln1b, Wf2, bf2, out);
}

// Round 6
// 250.448 us; speedup vs baseline: 1.9444x; 1.0990x over previous
//
#include <hip/hip_runtime.h>

#define N_NODES 50000
#define NFEAT 128
#define NEDGE 800000
#define NGRAPH 512
#define NCE 64
#define EPS 1e-5f
#define NBUCK 196            // ceil(50000/256) buckets of 256 nodes
#define EPB 4096             // edges per bucket_scatter block
#define BCAP 6144            // fixed per-bucket capacity (avg 4082, sigma 64 -> +32 sigma)

typedef short s8v __attribute__((ext_vector_type(8)));
typedef float f4v __attribute__((ext_vector_type(4)));

// ---------- bf16 helpers (manual, bit-exact RNE) ----------
static __device__ __forceinline__ unsigned short f2bf(float f) {
    unsigned int u = __float_as_uint(f);
    unsigned int r = u + 0x7fffu + ((u >> 16) & 1u);
    return (unsigned short)(r >> 16);
}
static __device__ __forceinline__ float bf_lo(unsigned int packed) {
    return __uint_as_float(packed << 16);
}
static __device__ __forceinline__ float bf_hi(unsigned int packed) {
    return __uint_as_float(packed & 0xffff0000u);
}
static __device__ __forceinline__ float bf_us(unsigned short us) {
    return __uint_as_float(((unsigned int)us) << 16);
}

// ---------- 1. bucket scatter: packed records, fixed-capacity buckets ----------
// rec = src | dst<<16 (node ids < 65536). One atomicAdd per bucket per block.
__global__ __launch_bounds__(256) void bucket_scatter_kernel(
    const int* __restrict__ ei, int* __restrict__ bucketCursor,
    unsigned int* __restrict__ recbuf, int E)
{
    __shared__ int hist[NBUCK];
    __shared__ int lbase[NBUCK];
    __shared__ int gbase[NBUCK];
    __shared__ int cur[NBUCK];
    __shared__ int scanbuf[256];
    __shared__ unsigned int staging[EPB];
    int tid = threadIdx.x;
    if (tid < NBUCK) { hist[tid] = 0; cur[tid] = 0; }
    __syncthreads();

    unsigned int rec[EPB / 256];
    int e0 = blockIdx.x * EPB + tid;
#pragma unroll
    for (int i = 0; i < EPB / 256; ++i) {
        int e = e0 + i * 256;
        if (e < E) {
            unsigned int sv = (unsigned)ei[e];
            unsigned int dv = (unsigned)ei[E + e];
            rec[i] = sv | (dv << 16);
            atomicAdd(&hist[dv >> 8], 1);
        } else {
            rec[i] = 0xffffffffu;   // impossible as a real record (src would be 65535 >= N)
        }
    }
    __syncthreads();
    int v = (tid < NBUCK) ? hist[tid] : 0;
    scanbuf[tid] = v; __syncthreads();
    for (int off = 1; off < 256; off <<= 1) {
        int t = (tid >= off) ? scanbuf[tid - off] : 0;
        __syncthreads();
        scanbuf[tid] += t;
        __syncthreads();
    }
    if (tid < NBUCK) lbase[tid] = scanbuf[tid] - v;
    int total = scanbuf[255];
    if (tid < NBUCK) gbase[tid] = (v > 0) ? atomicAdd(&bucketCursor[tid], v) : 0;
    __syncthreads();
#pragma unroll
    for (int i = 0; i < EPB / 256; ++i) {
        if (rec[i] != 0xffffffffu) {
            int b = rec[i] >> 24;       // dst >> 8
            int loc = atomicAdd(&cur[b], 1);
            staging[lbase[b] + loc] = rec[i];
        }
    }
    __syncthreads();
    for (int s = tid; s < total; s += 256) {
        unsigned int r = staging[s];
        int b = r >> 24;
        int pos = gbase[b] + (s - lbase[b]);
        if (pos < BCAP) recbuf[(size_t)b * BCAP + pos] = r;
    }
}

// ---------- 2. per-bucket CSR finalize: rowbeg + deg + dinv + coalesced colidx ----------
__global__ __launch_bounds__(256) void bucket_csr_kernel(
    const unsigned int* __restrict__ recbuf, const int* __restrict__ bucketCursor,
    int* __restrict__ rowbeg, unsigned short* __restrict__ deg,
    float* __restrict__ dinv, unsigned short* __restrict__ colidx)
{
    __shared__ int cnt[256];
    __shared__ int cur[256];
    __shared__ int scanbuf[256];
    __shared__ unsigned short stage[BCAP];
    int b = blockIdx.x, tid = threadIdx.x;
    int base = b * BCAP;
    int len = bucketCursor[b]; if (len > BCAP) len = BCAP;
    cnt[tid] = 0;
    __syncthreads();
    for (int s = tid; s < len; s += 256) {
        unsigned int r = recbuf[base + s];
        atomicAdd(&cnt[(r >> 16) & 255], 1);
    }
    __syncthreads();
    int v = cnt[tid];
    scanbuf[tid] = v; __syncthreads();
    for (int off = 1; off < 256; off <<= 1) {
        int t = (tid >= off) ? scanbuf[tid - off] : 0;
        __syncthreads();
        scanbuf[tid] += t;
        __syncthreads();
    }
    int excl = scanbuf[tid] - v;
    int node = b * 256 + tid;
    if (node < N_NODES) {
        rowbeg[node] = base + excl;
        deg[node] = (unsigned short)v;
        dinv[node] = rsqrtf((float)v + 1.0f);
    }
    cur[tid] = excl;
    __syncthreads();
    for (int s = tid; s < len; s += 256) {
        unsigned int r = recbuf[base + s];
        int pos = atomicAdd(&cur[(r >> 16) & 255], 1);
        stage[pos] = (unsigned short)(r & 0xffffu);
    }
    __syncthreads();
    for (int s = tid; s < len; s += 256) colidx[base + s] = stage[s];
}

// ---------- weight cast+transpose: WT[n][k] = bf16(W[k][n]) ----------
__global__ __launch_bounds__(256) void wcast_kernel(
    const float* __restrict__ W1, const float* __restrict__ W2,
    unsigned short* __restrict__ WT1, unsigned short* __restrict__ WT2)
{
    const float* W = blockIdx.y ? W2 : W1;
    unsigned short* WT = blockIdx.y ? WT2 : WT1;
    int idx = blockIdx.x * 256 + threadIdx.x;   // 64 blocks x 256 = 16384
    int k = idx >> 7, n = idx & 127;
    WT[n * 128 + k] = f2bf(W[idx]);
}

// ---------- MFMA GEMM: HS[r][c] = bf16( (A @ W)[r][c] * dinv[r] ) ----------
template<bool FP32IN>
__global__ __launch_bounds__(256) void gemm_mfma_kernel(
    const void* __restrict__ Ain, const unsigned short* __restrict__ WTg,
    const float* __restrict__ dinv, unsigned short* __restrict__ HS, int nrows)
{
    __shared__ unsigned short as[128 * 128];   // 32 KB; reused for result staging
    __shared__ unsigned short wt[128 * 128];   // 32 KB
    const int tid = threadIdx.x;
    const int row0 = blockIdx.x * 128;

    {
        const uint4* src = reinterpret_cast<const uint4*>(WTg);
        uint4* dst = reinterpret_cast<uint4*>(wt);
#pragma unroll
        for (int i = 0; i < 8; ++i) dst[tid + i * 256] = src[tid + i * 256];
    }
    if (FP32IN) {
        const float* X = (const float*)Ain;
#pragma unroll
        for (int i = 0; i < 16; ++i) {
            int f = tid + i * 256;
            int r = f >> 5, c4 = f & 31;
            int rr = row0 + r; if (rr >= nrows) rr = nrows - 1;
            float4 v = *reinterpret_cast<const float4*>(&X[rr * 128 + c4 * 4]);
            ushort4 o;
            o.x = f2bf(v.x); o.y = f2bf(v.y); o.z = f2bf(v.z); o.w = f2bf(v.w);
            *reinterpret_cast<ushort4*>(&as[r * 128 + c4 * 4]) = o;
        }
    } else {
        const unsigned short* X = (const unsigned short*)Ain;
#pragma unroll
        for (int i = 0; i < 8; ++i) {
            int f = tid + i * 256;
            int r = f >> 4, c8 = f & 15;
            int rr = row0 + r; if (rr >= nrows) rr = nrows - 1;
            *reinterpret_cast<uint4*>(&as[r * 128 + c8 * 8]) =
                *reinterpret_cast<const uint4*>(&X[rr * 128 + c8 * 8]);
        }
    }
    __syncthreads();

    const int w = tid >> 6;
    const int lane = tid & 63;
    const int quad = lane >> 4;
    const int col0 = lane & 15;

    s8v afr[2][4];
#pragma unroll
    for (int rt = 0; rt < 2; ++rt)
#pragma unroll
        for (int kt = 0; kt < 4; ++kt)
            afr[rt][kt] = *reinterpret_cast<const s8v*>(
                &as[(w * 32 + rt * 16 + col0) * 128 + kt * 32 + quad * 8]);

    f4v acc[2][8];
#pragma unroll
    for (int rt = 0; rt < 2; ++rt)
#pragma unroll
        for (int nt = 0; nt < 8; ++nt)
            acc[rt][nt] = (f4v){0.f, 0.f, 0.f, 0.f};

#pragma unroll
    for (int nt = 0; nt < 8; ++nt) {
        s8v bfr[4];
#pragma unroll
        for (int kt = 0; kt < 4; ++kt)
            bfr[kt] = *reinterpret_cast<const s8v*>(
                &wt[(nt * 16 + col0) * 128 + kt * 32 + quad * 8]);
#pragma unroll
        for (int rt = 0; rt < 2; ++rt)
#pragma unroll
            for (int kt = 0; kt < 4; ++kt)
                acc[rt][nt] = __builtin_amdgcn_mfma_f32_16x16x32_bf16(
                    afr[rt][kt], bfr[kt], acc[rt][nt], 0, 0, 0);
    }

    float dv[2][4];
#pragma unroll
    for (int rt = 0; rt < 2; ++rt)
#pragma unroll
        for (int reg = 0; reg < 4; ++reg) {
            int r = row0 + w * 32 + rt * 16 + quad * 4 + reg;
            dv[rt][reg] = (r < nrows) ? dinv[r] : 0.f;
        }

#pragma unroll
    for (int rt = 0; rt < 2; ++rt)
#pragma unroll
        for (int nt = 0; nt < 8; ++nt)
#pragma unroll
            for (int reg = 0; reg < 4; ++reg) {
                int rl = w * 32 + rt * 16 + quad * 4 + reg;
                as[rl * 128 + nt * 16 + col0] = f2bf(acc[rt][nt][reg] * dv[rt][reg]);
            }
    __syncthreads();
#pragma unroll
    for (int i = 0; i < 8; ++i) {
        int f = tid + i * 256;
        int r = f >> 4, c8 = f & 15;
        if (row0 + r < nrows)
            *reinterpret_cast<uint4*>(&HS[(size_t)(row0 + r) * 128 + c8 * 8]) =
                *reinterpret_cast<const uint4*>(&as[r * 128 + c8 * 8]);
    }
}

// ---------- aggregation: one wave per node, 16/8/2/1 MLP ladder, bf16 out ----------
__global__ __launch_bounds__(256) void aggregate_kernel(
    const unsigned int* __restrict__ H,
    const int* __restrict__ rowbeg, const unsigned short* __restrict__ deg,
    const unsigned short* __restrict__ colidx,
    const float* __restrict__ dinv, const float* __restrict__ bias,
    unsigned int* __restrict__ OUT, int n)
{
    int wid = (blockIdx.x * blockDim.x + threadIdx.x) >> 6;
    int lane = threadIdx.x & 63;
    if (wid >= n) return;
    unsigned int self = H[wid * 64 + lane];
    float a0 = bf_lo(self), a1 = bf_hi(self);
    float c0 = 0.f, c1 = 0.f, d0 = 0.f, d1 = 0.f, e0 = 0.f, e1 = 0.f;
    float f0 = 0.f, f1 = 0.f, g0 = 0.f, g1 = 0.f;
    float h0 = 0.f, h1 = 0.f, i0 = 0.f, i1 = 0.f;
    int beg = rowbeg[wid];
    int end = beg + (int)deg[wid];
    for (int base = beg; base < end; base += 64) {
        int m = end - base; if (m > 64) m = 64;
        int idx = (lane < m) ? (int)colidx[base + lane] : 0;
        int j = 0;
        for (; j + 16 <= m; j += 16) {
            unsigned int t[16];
#pragma unroll
            for (int q = 0; q < 16; ++q) {
                int u = __shfl(idx, j + q);
                t[q] = H[u * 64 + lane];
            }
            a0 += bf_lo(t[0]) + bf_lo(t[8]);   a1 += bf_hi(t[0]) + bf_hi(t[8]);
            c0 += bf_lo(t[1]) + bf_lo(t[9]);   c1 += bf_hi(t[1]) + bf_hi(t[9]);
            d0 += bf_lo(t[2]) + bf_lo(t[10]);  d1 += bf_hi(t[2]) + bf_hi(t[10]);
            e0 += bf_lo(t[3]) + bf_lo(t[11]);  e1 += bf_hi(t[3]) + bf_hi(t[11]);
            f0 += bf_lo(t[4]) + bf_lo(t[12]);  f1 += bf_hi(t[4]) + bf_hi(t[12]);
            g0 += bf_lo(t[5]) + bf_lo(t[13]);  g1 += bf_hi(t[5]) + bf_hi(t[13]);
            h0 += bf_lo(t[6]) + bf_lo(t[14]);  h1 += bf_hi(t[6]) + bf_hi(t[14]);
            i0 += bf_lo(t[7]) + bf_lo(t[15]);  i1 += bf_hi(t[7]) + bf_hi(t[15]);
        }
        for (; j + 8 <= m; j += 8) {
            unsigned int t[8];
#pragma unroll
            for (int q = 0; q < 8; ++q) {
                int u = __shfl(idx, j + q);
                t[q] = H[u * 64 + lane];
            }
            a0 += bf_lo(t[0]) + bf_lo(t[4]);   a1 += bf_hi(t[0]) + bf_hi(t[4]);
            c0 += bf_lo(t[1]) + bf_lo(t[5]);   c1 += bf_hi(t[1]) + bf_hi(t[5]);
            d0 += bf_lo(t[2]) + bf_lo(t[6]);   d1 += bf_hi(t[2]) + bf_hi(t[6]);
            e0 += bf_lo(t[3]) + bf_lo(t[7]);   e1 += bf_hi(t[3]) + bf_hi(t[7]);
        }
        for (; j + 2 <= m; j += 2) {
            int u0 = __shfl(idx, j + 0);
            int u1 = __shfl(idx, j + 1);
            unsigned int t0 = H[u0 * 64 + lane];
            unsigned int t1 = H[u1 * 64 + lane];
            a0 += bf_lo(t0); a1 += bf_hi(t0);
            c0 += bf_lo(t1); c1 += bf_hi(t1);
        }
        if (j < m) {
            int u0 = __shfl(idx, j);
            unsigned int t0 = H[u0 * 64 + lane];
            a0 += bf_lo(t0); a1 += bf_hi(t0);
        }
    }
    a0 += c0 + d0 + e0 + f0 + g0 + h0 + i0;
    a1 += c1 + d1 + e1 + f1 + g1 + h1 + i1;
    float s = dinv[wid];
    float b0 = bias[lane * 2 + 0];
    float b1 = bias[lane * 2 + 1];
    float o0 = fmaxf(fmaf(a0, s, b0), 0.f);
    float o1 = fmaxf(fmaf(a1, s, b1), 0.f);
    OUT[wid * 64 + lane] = (unsigned int)f2bf(o0) | ((unsigned int)f2bf(o1) << 16);
}

// ---------- fused pool + tail: binary-search graph range, pool bf16, 3 layers + 2 LN ----------
__global__ __launch_bounds__(256) void tail_kernel(
    const unsigned short* __restrict__ h2b, const int* __restrict__ batch,
    const int* __restrict__ cell, const float* __restrict__ emb,
    const float* __restrict__ Wc, const float* __restrict__ bc,
    const float* __restrict__ lncw, const float* __restrict__ lncb,
    const float* __restrict__ Wf1, const float* __restrict__ bf1,
    const float* __restrict__ ln1w, const float* __restrict__ ln1b,
    const float* __restrict__ Wf2, const float* __restrict__ bf2,
    float* __restrict__ out)
{
    __shared__ __align__(16) float comb[192];
    __shared__ __align__(16) float part[8][132];
    __shared__ float red[4];
    __shared__ __align__(16) float vec[128];
    const int gi = blockIdx.x;
    const int tid = threadIdx.x;
    const int cg = tid & 31;
    const int ks = tid >> 5;

    // graph node range via lower_bound (redundant across threads; batch is L1/L2-hot)
    int lo = 0, hi = N_NODES;
    while (lo < hi) { int mid = (lo + hi) >> 1; if (batch[mid] < gi) lo = mid + 1; else hi = mid; }
    int lo2 = lo, hi2 = N_NODES;
    while (lo2 < hi2) { int mid = (lo2 + hi2) >> 1; if (batch[mid] < gi + 1) lo2 = mid + 1; else hi2 = mid; }

    // pool: half = tid>>7 sums every other node for feature j = tid&127
    {
        int half = tid >> 7;
        int j = tid & 127;
        float acc = 0.f;
        for (int v = lo + half; v < lo2; v += 2)
            acc += bf_us(h2b[(size_t)v * 128 + j]);
        part[half][j] = acc;
    }
    __syncthreads();
    if (tid < 128) comb[tid] = part[0][tid] + part[1][tid];
    else if (tid < 192) comb[tid] = emb[cell[gi] * 64 + (tid - 128)];
    __syncthreads();

    // ---- layer A: comb @ Wc ----
    {
        float c[24];
#pragma unroll
        for (int i = 0; i < 6; ++i) {
            float4 t = *reinterpret_cast<const float4*>(&comb[ks * 24 + i * 4]);
            c[i * 4 + 0] = t.x; c[i * 4 + 1] = t.y; c[i * 4 + 2] = t.z; c[i * 4 + 3] = t.w;
        }
        float a0 = 0.f, a1 = 0.f, a2 = 0.f, a3 = 0.f;
#pragma unroll
        for (int i = 0; i < 24; ++i) {
            const float4 w = *reinterpret_cast<const float4*>(&Wc[(ks * 24 + i) * 128 + cg * 4]);
            a0 = fmaf(c[i], w.x, a0);
            a1 = fmaf(c[i], w.y, a1);
            a2 = fmaf(c[i], w.z, a2);
            a3 = fmaf(c[i], w.w, a3);
        }
        float4 o; o.x = a0; o.y = a1; o.z = a2; o.w = a3;
        *reinterpret_cast<float4*>(&part[ks][cg * 4]) = o;
    }
    __syncthreads();
    {
        float y = 0.f;
        if (tid < 128) {
            y = bc[tid];
#pragma unroll
            for (int s = 0; s < 8; ++s) y += part[s][tid];
        }
        float s1 = (tid < 128) ? y : 0.f;
        float s2 = (tid < 128) ? y * y : 0.f;
        if (tid < 128) {
#pragma unroll
            for (int off = 32; off > 0; off >>= 1) {
                s1 += __shfl_down(s1, off);
                s2 += __shfl_down(s2, off);
            }
            if ((tid & 63) == 0) { red[(tid >> 6) * 2] = s1; red[(tid >> 6) * 2 + 1] = s2; }
        }
        __syncthreads();
        float mu = (red[0] + red[2]) * (1.f / 128.f);
        float ms = (red[1] + red[3]) * (1.f / 128.f);
        float var = ms - mu * mu;
        if (tid < 128) {
            float yv = (y - mu) * rsqrtf(var + EPS) * lncw[tid] + lncb[tid];
            vec[tid] = fmaxf(yv, 0.f);
        }
    }
    __syncthreads();

    // ---- layer B: vec @ Wf1, relu, LN ----
    {
        float c[16];
#pragma unroll
        for (int i = 0; i < 4; ++i) {
            float4 t = *reinterpret_cast<const float4*>(&vec[ks * 16 + i * 4]);
            c[i * 4 + 0] = t.x; c[i * 4 + 1] = t.y; c[i * 4 + 2] = t.z; c[i * 4 + 3] = t.w;
        }
        float a0 = 0.f, a1 = 0.f, a2 = 0.f, a3 = 0.f;
#pragma unroll
        for (int i = 0; i < 16; ++i) {
            const float4 w = *reinterpret_cast<const float4*>(&Wf1[(ks * 16 + i) * 128 + cg * 4]);
            a0 = fmaf(c[i], w.x, a0);
            a1 = fmaf(c[i], w.y, a1);
            a2 = fmaf(c[i], w.z, a2);
            a3 = fmaf(c[i], w.w, a3);
        }
        float4 o; o.x = a0; o.y = a1; o.z = a2; o.w = a3;
        *reinterpret_cast<float4*>(&part[ks][cg * 4]) = o;
    }
    __syncthreads();
    {
        float y = 0.f;
        if (tid < 128) {
            y = bf1[tid];
#pragma unroll
            for (int s = 0; s < 8; ++s) y += part[s][tid];
            y = fmaxf(y, 0.f);                 // relu BEFORE LN
        }
        float s1 = (tid < 128) ? y : 0.f;
        float s2 = (tid < 128) ? y * y : 0.f;
        if (tid < 128) {
#pragma unroll
            for (int off = 32; off > 0; off >>= 1) {
                s1 += __shfl_down(s1, off);
                s2 += __shfl_down(s2, off);
            }
            if ((tid & 63) == 0) { red[(tid >> 6) * 2] = s1; red[(tid >> 6) * 2 + 1] = s2; }
        }
        __syncthreads();
        float mu = (red[0] + red[2]) * (1.f / 128.f);
        float ms = (red[1] + red[3]) * (1.f / 128.f);
        float var = ms - mu * mu;
        if (tid < 128)
            vec[tid] = (y - mu) * rsqrtf(var + EPS) * ln1w[tid] + ln1b[tid];   // no relu
    }
    __syncthreads();

    // ---- layer C: vec @ Wf2 ----
    {
        float c[16];
#pragma unroll
        for (int i = 0; i < 4; ++i) {
            float4 t = *reinterpret_cast<const float4*>(&vec[ks * 16 + i * 4]);
            c[i * 4 + 0] = t.x; c[i * 4 + 1] = t.y; c[i * 4 + 2] = t.z; c[i * 4 + 3] = t.w;
        }
        float a0 = 0.f, a1 = 0.f, a2 = 0.f, a3 = 0.f;
#pragma unroll
        for (int i = 0; i < 16; ++i) {
            const float4 w = *reinterpret_cast<const float4*>(&Wf2[(ks * 16 + i) * 128 + cg * 4]);
            a0 = fmaf(c[i], w.x, a0);
            a1 = fmaf(c[i], w.y, a1);
            a2 = fmaf(c[i], w.z, a2);
            a3 = fmaf(c[i], w.w, a3);
        }
        float4 o; o.x = a0; o.y = a1; o.z = a2; o.w = a3;
        *reinterpret_cast<float4*>(&part[ks][cg * 4]) = o;
    }
    __syncthreads();
    if (tid < 128) {
        float y = bf2[tid];
#pragma unroll
        for (int s = 0; s < 8; ++s) y += part[s][tid];
        out[gi * 128 + tid] = y;
    }
}

// ---------- host launch ----------
extern "C" void kernel_launch(void* const* d_in, const int* in_sizes, int n_in,
                              void* d_out, int out_size, void* d_ws, size_t ws_size,
                              hipStream_t stream) {
    const float* x    = (const float*)d_in[0];
    const int*   ei   = (const int*)d_in[1];
    const int*   batch= (const int*)d_in[2];
    const int*   cell = (const int*)d_in[3];
    const float* W1   = (const float*)d_in[4];
    const float* b1   = (const float*)d_in[5];
    const float* W2   = (const float*)d_in[6];
    const float* b2   = (const float*)d_in[7];
    const float* emb  = (const float*)d_in[8];
    const float* Wc   = (const float*)d_in[9];
    const float* bc   = (const float*)d_in[10];
    const float* lncw = (const float*)d_in[11];
    const float* lncb = (const float*)d_in[12];
    const float* Wf1  = (const float*)d_in[13];
    const float* bf1  = (const float*)d_in[14];
    const float* ln1w = (const float*)d_in[15];
    const float* ln1b = (const float*)d_in[16];
    const float* Wf2  = (const float*)d_in[17];
    const float* bf2  = (const float*)d_in[18];
    float* out = (float*)d_out;

    char* ws = (char*)d_ws;
    size_t off = 0;
    auto alloc = [&](size_t bytes) { char* p = ws + off; off = (off + bytes + 255) & ~size_t(255); return p; };
    float*          dinv        = (float*)alloc(N_NODES * 4);
    int*            rowbeg      = (int*)  alloc(N_NODES * 4);
    unsigned short* deg         = (unsigned short*)alloc(N_NODES * 2);
    unsigned short* colidx      = (unsigned short*)alloc((size_t)NBUCK * BCAP * 2);
    int*            bucketCursor= (int*)  alloc(NBUCK * 4);
    unsigned int*   recbuf      = (unsigned int*)alloc((size_t)NBUCK * BCAP * 4);
    unsigned short* wt1         = (unsigned short*)alloc(128 * 128 * 2);
    unsigned short* wt2         = (unsigned short*)alloc(128 * 128 * 2);
    unsigned short* hs          = (unsigned short*)alloc((size_t)N_NODES * 128 * 2);
    unsigned short* h1          = (unsigned short*)alloc((size_t)N_NODES * 128 * 2);
    unsigned short* h2b         = (unsigned short*)alloc((size_t)N_NODES * 128 * 2);

    const int nbEdge = (NEDGE + EPB - 1) / EPB;        // 196
    const int nbGemm = (N_NODES + 127) / 128;          // 391
    const int nbAgg  = (N_NODES + 3) / 4;              // 12500

    hipMemsetAsync(bucketCursor, 0, NBUCK * 4, stream);

    // weight cast (independent)
    wcast_kernel<<<dim3(64, 2), 256, 0, stream>>>(W1, W2, wt1, wt2);

    // CSR build (2 kernels)
    bucket_scatter_kernel<<<nbEdge, 256, 0, stream>>>(ei, bucketCursor, recbuf, NEDGE);
    bucket_csr_kernel<<<NBUCK, 256, 0, stream>>>(recbuf, bucketCursor, rowbeg, deg, dinv, colidx);

    // conv1
    gemm_mfma_kernel<true><<<nbGemm, 256, 0, stream>>>(x, wt1, dinv, hs, N_NODES);
    aggregate_kernel<<<nbAgg, 256, 0, stream>>>((const unsigned int*)hs, rowbeg, deg, colidx,
                                                dinv, b1, (unsigned int*)h1, N_NODES);
    // conv2
    gemm_mfma_kernel<false><<<nbGemm, 256, 0, stream>>>(h1, wt2, dinv, hs, N_NODES);
    aggregate_kernel<<<nbAgg, 256, 0, stream>>>((const unsigned int*)hs, rowbeg, deg, colidx,
                                                dinv, b2, (unsigned int*)h2b, N_NODES);
    // fused pool + tail
    tail_kernel<<<NGRAPH, 256, 0, stream>>>(h2b, batch, cell, emb, Wc, bc, lncw, lncb,
                                            Wf1, bf1, ln1w, ln1b, Wf2, bf2, out);
}

// Round 7
// 243.234 us; speedup vs baseline: 2.0021x; 1.0297x over previous
//
#include <hip/hip_runtime.h>

#define N_NODES 50000
#define NFEAT 128
#define NEDGE 800000
#define NGRAPH 512
#define NCE 64
#define EPS 1e-5f
#define NBUCK 196            // ceil(50000/256) buckets of 256 nodes
#define EPB 4096             // edges per bucket_scatter block
#define BCAP 6144            // fixed per-bucket capacity (avg 4082, sigma 64 -> +32 sigma)

typedef short s8v __attribute__((ext_vector_type(8)));
typedef float f4v __attribute__((ext_vector_type(4)));

// ---------- bf16 helpers (manual, bit-exact RNE) ----------
static __device__ __forceinline__ unsigned short f2bf(float f) {
    unsigned int u = __float_as_uint(f);
    unsigned int r = u + 0x7fffu + ((u >> 16) & 1u);
    return (unsigned short)(r >> 16);
}
static __device__ __forceinline__ float bf_lo(unsigned int packed) {
    return __uint_as_float(packed << 16);
}
static __device__ __forceinline__ float bf_hi(unsigned int packed) {
    return __uint_as_float(packed & 0xffff0000u);
}
static __device__ __forceinline__ float bf_us(unsigned short us) {
    return __uint_as_float(((unsigned int)us) << 16);
}

// ---------- 0. weight cast+transpose + cursor init ----------
__global__ __launch_bounds__(256) void wcast_kernel(
    const float* __restrict__ W1, const float* __restrict__ W2,
    unsigned short* __restrict__ WT1, unsigned short* __restrict__ WT2,
    int* __restrict__ bucketCursor)
{
    if (blockIdx.x == 0 && blockIdx.y == 0 && threadIdx.x < NBUCK)
        bucketCursor[threadIdx.x] = 0;
    const float* W = blockIdx.y ? W2 : W1;
    unsigned short* WT = blockIdx.y ? WT2 : WT1;
    int idx = blockIdx.x * 256 + threadIdx.x;   // 64 blocks x 256 = 16384
    int k = idx >> 7, n = idx & 127;
    WT[n * 128 + k] = f2bf(W[idx]);
}

// ---------- 1. bucket scatter: packed records, fixed-capacity buckets ----------
__global__ __launch_bounds__(256) void bucket_scatter_kernel(
    const int* __restrict__ ei, int* __restrict__ bucketCursor,
    unsigned int* __restrict__ recbuf, int E)
{
    __shared__ int hist[NBUCK];
    __shared__ int lbase[NBUCK];
    __shared__ int gbase[NBUCK];
    __shared__ int cur[NBUCK];
    __shared__ int scanbuf[256];
    __shared__ unsigned int staging[EPB];
    int tid = threadIdx.x;
    if (tid < NBUCK) { hist[tid] = 0; cur[tid] = 0; }
    __syncthreads();

    unsigned int rec[EPB / 256];
    int e0 = blockIdx.x * EPB + tid;
#pragma unroll
    for (int i = 0; i < EPB / 256; ++i) {
        int e = e0 + i * 256;
        if (e < E) {
            unsigned int sv = (unsigned)ei[e];
            unsigned int dv = (unsigned)ei[E + e];
            rec[i] = sv | (dv << 16);
            atomicAdd(&hist[dv >> 8], 1);
        } else {
            rec[i] = 0xffffffffu;
        }
    }
    __syncthreads();
    int v = (tid < NBUCK) ? hist[tid] : 0;
    scanbuf[tid] = v; __syncthreads();
    for (int off = 1; off < 256; off <<= 1) {
        int t = (tid >= off) ? scanbuf[tid - off] : 0;
        __syncthreads();
        scanbuf[tid] += t;
        __syncthreads();
    }
    if (tid < NBUCK) lbase[tid] = scanbuf[tid] - v;
    int total = scanbuf[255];
    if (tid < NBUCK) gbase[tid] = (v > 0) ? atomicAdd(&bucketCursor[tid], v) : 0;
    __syncthreads();
#pragma unroll
    for (int i = 0; i < EPB / 256; ++i) {
        if (rec[i] != 0xffffffffu) {
            int b = rec[i] >> 24;       // dst >> 8
            int loc = atomicAdd(&cur[b], 1);
            staging[lbase[b] + loc] = rec[i];
        }
    }
    __syncthreads();
    for (int s = tid; s < total; s += 256) {
        unsigned int r = staging[s];
        int b = r >> 24;
        int pos = gbase[b] + (s - lbase[b]);
        if (pos < BCAP) recbuf[(size_t)b * BCAP + pos] = r;
    }
}

// ---------- 2. per-bucket CSR finalize ----------
__global__ __launch_bounds__(256) void bucket_csr_kernel(
    const unsigned int* __restrict__ recbuf, const int* __restrict__ bucketCursor,
    int* __restrict__ rowbeg, unsigned short* __restrict__ deg,
    float* __restrict__ dinv, unsigned short* __restrict__ colidx)
{
    __shared__ int cnt[256];
    __shared__ int cur[256];
    __shared__ int scanbuf[256];
    __shared__ unsigned short stage[BCAP];
    int b = blockIdx.x, tid = threadIdx.x;
    int base = b * BCAP;
    int len = bucketCursor[b]; if (len > BCAP) len = BCAP;
    cnt[tid] = 0;
    __syncthreads();
    for (int s = tid; s < len; s += 256) {
        unsigned int r = recbuf[base + s];
        atomicAdd(&cnt[(r >> 16) & 255], 1);
    }
    __syncthreads();
    int v = cnt[tid];
    scanbuf[tid] = v; __syncthreads();
    for (int off = 1; off < 256; off <<= 1) {
        int t = (tid >= off) ? scanbuf[tid - off] : 0;
        __syncthreads();
        scanbuf[tid] += t;
        __syncthreads();
    }
    int excl = scanbuf[tid] - v;
    int node = b * 256 + tid;
    if (node < N_NODES) {
        rowbeg[node] = base + excl;
        deg[node] = (unsigned short)v;
        dinv[node] = rsqrtf((float)v + 1.0f);
    }
    cur[tid] = excl;
    __syncthreads();
    for (int s = tid; s < len; s += 256) {
        unsigned int r = recbuf[base + s];
        int pos = atomicAdd(&cur[(r >> 16) & 255], 1);
        stage[pos] = (unsigned short)(r & 0xffffu);
    }
    __syncthreads();
    for (int s = tid; s < len; s += 256) colidx[base + s] = stage[s];
}

// ---------- MFMA GEMM: HS[r][c] = bf16( (A @ W)[r][c] * dinv[r] ) ----------
template<bool FP32IN>
__global__ __launch_bounds__(256) void gemm_mfma_kernel(
    const void* __restrict__ Ain, const unsigned short* __restrict__ WTg,
    const float* __restrict__ dinv, unsigned short* __restrict__ HS, int nrows)
{
    __shared__ unsigned short as[128 * 128];   // 32 KB; reused for result staging
    __shared__ unsigned short wt[128 * 128];   // 32 KB
    const int tid = threadIdx.x;
    const int row0 = blockIdx.x * 128;

    {
        const uint4* src = reinterpret_cast<const uint4*>(WTg);
        uint4* dst = reinterpret_cast<uint4*>(wt);
#pragma unroll
        for (int i = 0; i < 8; ++i) dst[tid + i * 256] = src[tid + i * 256];
    }
    if (FP32IN) {
        const float* X = (const float*)Ain;
#pragma unroll
        for (int i = 0; i < 16; ++i) {
            int f = tid + i * 256;
            int r = f >> 5, c4 = f & 31;
            int rr = row0 + r; if (rr >= nrows) rr = nrows - 1;
            float4 v = *reinterpret_cast<const float4*>(&X[rr * 128 + c4 * 4]);
            ushort4 o;
            o.x = f2bf(v.x); o.y = f2bf(v.y); o.z = f2bf(v.z); o.w = f2bf(v.w);
            *reinterpret_cast<ushort4*>(&as[r * 128 + c4 * 4]) = o;
        }
    } else {
        const unsigned short* X = (const unsigned short*)Ain;
#pragma unroll
        for (int i = 0; i < 8; ++i) {
            int f = tid + i * 256;
            int r = f >> 4, c8 = f & 15;
            int rr = row0 + r; if (rr >= nrows) rr = nrows - 1;
            *reinterpret_cast<uint4*>(&as[r * 128 + c8 * 8]) =
                *reinterpret_cast<const uint4*>(&X[rr * 128 + c8 * 8]);
        }
    }
    __syncthreads();

    const int w = tid >> 6;
    const int lane = tid & 63;
    const int quad = lane >> 4;
    const int col0 = lane & 15;

    s8v afr[2][4];
#pragma unroll
    for (int rt = 0; rt < 2; ++rt)
#pragma unroll
        for (int kt = 0; kt < 4; ++kt)
            afr[rt][kt] = *reinterpret_cast<const s8v*>(
                &as[(w * 32 + rt * 16 + col0) * 128 + kt * 32 + quad * 8]);

    f4v acc[2][8];
#pragma unroll
    for (int rt = 0; rt < 2; ++rt)
#pragma unroll
        for (int nt = 0; nt < 8; ++nt)
            acc[rt][nt] = (f4v){0.f, 0.f, 0.f, 0.f};

#pragma unroll
    for (int nt = 0; nt < 8; ++nt) {
        s8v bfr[4];
#pragma unroll
        for (int kt = 0; kt < 4; ++kt)
            bfr[kt] = *reinterpret_cast<const s8v*>(
                &wt[(nt * 16 + col0) * 128 + kt * 32 + quad * 8]);
#pragma unroll
        for (int rt = 0; rt < 2; ++rt)
#pragma unroll
            for (int kt = 0; kt < 4; ++kt)
                acc[rt][nt] = __builtin_amdgcn_mfma_f32_16x16x32_bf16(
                    afr[rt][kt], bfr[kt], acc[rt][nt], 0, 0, 0);
    }

    float dv[2][4];
#pragma unroll
    for (int rt = 0; rt < 2; ++rt)
#pragma unroll
        for (int reg = 0; reg < 4; ++reg) {
            int r = row0 + w * 32 + rt * 16 + quad * 4 + reg;
            dv[rt][reg] = (r < nrows) ? dinv[r] : 0.f;
        }

#pragma unroll
    for (int rt = 0; rt < 2; ++rt)
#pragma unroll
        for (int nt = 0; nt < 8; ++nt)
#pragma unroll
            for (int reg = 0; reg < 4; ++reg) {
                int rl = w * 32 + rt * 16 + quad * 4 + reg;
                as[rl * 128 + nt * 16 + col0] = f2bf(acc[rt][nt][reg] * dv[rt][reg]);
            }
    __syncthreads();
#pragma unroll
    for (int i = 0; i < 8; ++i) {
        int f = tid + i * 256;
        int r = f >> 4, c8 = f & 15;
        if (row0 + r < nrows)
            *reinterpret_cast<uint4*>(&HS[(size_t)(row0 + r) * 128 + c8 * 8]) =
                *reinterpret_cast<const uint4*>(&as[r * 128 + c8 * 8]);
    }
}

// ---------- aggregation v3: one wave per node, PAIRED row gathers ----------
// lanes 0-31 load row u[2j], lanes 32-63 load row u[2j+1]; 8 B/lane (uint2).
// Self row folded in as neighbor 0. Cross-half combine via shfl_xor(32).
__global__ __launch_bounds__(256) void aggregate_kernel(
    const uint2* __restrict__ H2,                 // [N][32] uint2 (bf16x4)
    const int* __restrict__ rowbeg, const unsigned short* __restrict__ deg,
    const unsigned short* __restrict__ colidx,
    const float* __restrict__ dinv, const float* __restrict__ bias,
    uint2* __restrict__ OUT, int n)
{
    int wid = (blockIdx.x * blockDim.x + threadIdx.x) >> 6;
    int lane = threadIdx.x & 63;
    if (wid >= n) return;
    const int half = lane >> 5;
    const int sub = lane & 31;
    int beg = rowbeg[wid];
    int cnt = (int)deg[wid] + 1;                  // + self
    float s0 = 0.f, s1 = 0.f, s2 = 0.f, s3 = 0.f; // bank A
    float r0 = 0.f, r1 = 0.f, r2 = 0.f, r3 = 0.f; // bank B
    for (int base = 0; base < cnt; base += 64) {
        int m = cnt - base; if (m > 64) m = 64;
        int p = base + lane;
        int idx = 0;
        if (lane < m) idx = (p == 0) ? wid : (int)colidx[beg + p - 1];
        int j = 0;
        for (; j + 16 <= m; j += 16) {            // 8 pair-loads = 16 rows in flight
            uint2 t[8];
#pragma unroll
            for (int q = 0; q < 8; ++q) {
                int u = __shfl(idx, j + q * 2 + half);
                t[q] = H2[(size_t)u * 32 + sub];
            }
#pragma unroll
            for (int q = 0; q < 8; q += 2) {
                s0 += bf_lo(t[q].x); s1 += bf_hi(t[q].x);
                s2 += bf_lo(t[q].y); s3 += bf_hi(t[q].y);
                r0 += bf_lo(t[q + 1].x); r1 += bf_hi(t[q + 1].x);
                r2 += bf_lo(t[q + 1].y); r3 += bf_hi(t[q + 1].y);
            }
        }
        for (; j + 4 <= m; j += 4) {              // 2 pair-loads
            int ua = __shfl(idx, j + half);
            int ub = __shfl(idx, j + 2 + half);
            uint2 ta = H2[(size_t)ua * 32 + sub];
            uint2 tb = H2[(size_t)ub * 32 + sub];
            s0 += bf_lo(ta.x); s1 += bf_hi(ta.x);
            s2 += bf_lo(ta.y); s3 += bf_hi(ta.y);
            r0 += bf_lo(tb.x); r1 += bf_hi(tb.x);
            r2 += bf_lo(tb.y); r3 += bf_hi(tb.y);
        }
        if (j + 2 <= m) {                         // 1 pair-load
            int u = __shfl(idx, j + half);
            uint2 t = H2[(size_t)u * 32 + sub];
            s0 += bf_lo(t.x); s1 += bf_hi(t.x);
            s2 += bf_lo(t.y); s3 += bf_hi(t.y);
            j += 2;
        }
        if (j < m) {                              // odd singleton: half 0 only
            int u = __shfl(idx, j);
            uint2 t; t.x = 0u; t.y = 0u;
            if (half == 0) t = H2[(size_t)u * 32 + sub];
            s0 += bf_lo(t.x); s1 += bf_hi(t.x);
            s2 += bf_lo(t.y); s3 += bf_hi(t.y);
        }
    }
    s0 += r0; s1 += r1; s2 += r2; s3 += r3;
    s0 += __shfl_xor(s0, 32);
    s1 += __shfl_xor(s1, 32);
    s2 += __shfl_xor(s2, 32);
    s3 += __shfl_xor(s3, 32);
    if (half == 0) {
        float sc = dinv[wid];
        float4 bv = *reinterpret_cast<const float4*>(&bias[sub * 4]);
        float o0 = fmaxf(fmaf(s0, sc, bv.x), 0.f);
        float o1 = fmaxf(fmaf(s1, sc, bv.y), 0.f);
        float o2 = fmaxf(fmaf(s2, sc, bv.z), 0.f);
        float o3 = fmaxf(fmaf(s3, sc, bv.w), 0.f);
        uint2 o;
        o.x = (unsigned int)f2bf(o0) | ((unsigned int)f2bf(o1) << 16);
        o.y = (unsigned int)f2bf(o2) | ((unsigned int)f2bf(o3) << 16);
        OUT[(size_t)wid * 32 + sub] = o;
    }
}

// ---------- fused pool + tail ----------
__global__ __launch_bounds__(256) void tail_kernel(
    const unsigned short* __restrict__ h2b, const int* __restrict__ batch,
    const int* __restrict__ cell, const float* __restrict__ emb,
    const float* __restrict__ Wc, const float* __restrict__ bc,
    const float* __restrict__ lncw, const float* __restrict__ lncb,
    const float* __restrict__ Wf1, const float* __restrict__ bf1,
    const float* __restrict__ ln1w, const float* __restrict__ ln1b,
    const float* __restrict__ Wf2, const float* __restrict__ bf2,
    float* __restrict__ out)
{
    __shared__ __align__(16) float comb[192];
    __shared__ __align__(16) float part[8][132];
    __shared__ float red[4];
    __shared__ __align__(16) float vec[128];
    const int gi = blockIdx.x;
    const int tid = threadIdx.x;
    const int cg = tid & 31;
    const int ks = tid >> 5;

    int lo = 0, hi = N_NODES;
    while (lo < hi) { int mid = (lo + hi) >> 1; if (batch[mid] < gi) lo = mid + 1; else hi = mid; }
    int lo2 = lo, hi2 = N_NODES;
    while (lo2 < hi2) { int mid = (lo2 + hi2) >> 1; if (batch[mid] < gi + 1) lo2 = mid + 1; else hi2 = mid; }

    {
        int half = tid >> 7;
        int j = tid & 127;
        float acc = 0.f;
        for (int v = lo + half; v < lo2; v += 2)
            acc += bf_us(h2b[(size_t)v * 128 + j]);
        part[half][j] = acc;
    }
    __syncthreads();
    if (tid < 128) comb[tid] = part[0][tid] + part[1][tid];
    else if (tid < 192) comb[tid] = emb[cell[gi] * 64 + (tid - 128)];
    __syncthreads();

    // ---- layer A: comb @ Wc ----
    {
        float c[24];
#pragma unroll
        for (int i = 0; i < 6; ++i) {
            float4 t = *reinterpret_cast<const float4*>(&comb[ks * 24 + i * 4]);
            c[i * 4 + 0] = t.x; c[i * 4 + 1] = t.y; c[i * 4 + 2] = t.z; c[i * 4 + 3] = t.w;
        }
        float a0 = 0.f, a1 = 0.f, a2 = 0.f, a3 = 0.f;
#pragma unroll
        for (int i = 0; i < 24; ++i) {
            const float4 w = *reinterpret_cast<const float4*>(&Wc[(ks * 24 + i) * 128 + cg * 4]);
            a0 = fmaf(c[i], w.x, a0);
            a1 = fmaf(c[i], w.y, a1);
            a2 = fmaf(c[i], w.z, a2);
            a3 = fmaf(c[i], w.w, a3);
        }
        float4 o; o.x = a0; o.y = a1; o.z = a2; o.w = a3;
        *reinterpret_cast<float4*>(&part[ks][cg * 4]) = o;
    }
    __syncthreads();
    {
        float y = 0.f;
        if (tid < 128) {
            y = bc[tid];
#pragma unroll
            for (int s = 0; s < 8; ++s) y += part[s][tid];
        }
        float s1 = (tid < 128) ? y : 0.f;
        float s2 = (tid < 128) ? y * y : 0.f;
        if (tid < 128) {
#pragma unroll
            for (int off = 32; off > 0; off >>= 1) {
                s1 += __shfl_down(s1, off);
                s2 += __shfl_down(s2, off);
            }
            if ((tid & 63) == 0) { red[(tid >> 6) * 2] = s1; red[(tid >> 6) * 2 + 1] = s2; }
        }
        __syncthreads();
        float mu = (red[0] + red[2]) * (1.f / 128.f);
        float ms = (red[1] + red[3]) * (1.f / 128.f);
        float var = ms - mu * mu;
        if (tid < 128) {
            float yv = (y - mu) * rsqrtf(var + EPS) * lncw[tid] + lncb[tid];
            vec[tid] = fmaxf(yv, 0.f);
        }
    }
    __syncthreads();

    // ---- layer B: vec @ Wf1, relu, LN ----
    {
        float c[16];
#pragma unroll
        for (int i = 0; i < 4; ++i) {
            float4 t = *reinterpret_cast<const float4*>(&vec[ks * 16 + i * 4]);
            c[i * 4 + 0] = t.x; c[i * 4 + 1] = t.y; c[i * 4 + 2] = t.z; c[i * 4 + 3] = t.w;
        }
        float a0 = 0.f, a1 = 0.f, a2 = 0.f, a3 = 0.f;
#pragma unroll
        for (int i = 0; i < 16; ++i) {
            const float4 w = *reinterpret_cast<const float4*>(&Wf1[(ks * 16 + i) * 128 + cg * 4]);
            a0 = fmaf(c[i], w.x, a0);
            a1 = fmaf(c[i], w.y, a1);
            a2 = fmaf(c[i], w.z, a2);
            a3 = fmaf(c[i], w.w, a3);
        }
        float4 o; o.x = a0; o.y = a1; o.z = a2; o.w = a3;
        *reinterpret_cast<float4*>(&part[ks][cg * 4]) = o;
    }
    __syncthreads();
    {
        float y = 0.f;
        if (tid < 128) {
            y = bf1[tid];
#pragma unroll
            for (int s = 0; s < 8; ++s) y += part[s][tid];
            y = fmaxf(y, 0.f);                 // relu BEFORE LN
        }
        float s1 = (tid < 128) ? y : 0.f;
        float s2 = (tid < 128) ? y * y : 0.f;
        if (tid < 128) {
#pragma unroll
            for (int off = 32; off > 0; off >>= 1) {
                s1 += __shfl_down(s1, off);
                s2 += __shfl_down(s2, off);
            }
            if ((tid & 63) == 0) { red[(tid >> 6) * 2] = s1; red[(tid >> 6) * 2 + 1] = s2; }
        }
        __syncthreads();
        float mu = (red[0] + red[2]) * (1.f / 128.f);
        float ms = (red[1] + red[3]) * (1.f / 128.f);
        float var = ms - mu * mu;
        if (tid < 128)
            vec[tid] = (y - mu) * rsqrtf(var + EPS) * ln1w[tid] + ln1b[tid];   // no relu
    }
    __syncthreads();

    // ---- layer C: vec @ Wf2 ----
    {
        float c[16];
#pragma unroll
        for (int i = 0; i < 4; ++i) {
            float4 t = *reinterpret_cast<const float4*>(&vec[ks * 16 + i * 4]);
            c[i * 4 + 0] = t.x; c[i * 4 + 1] = t.y; c[i * 4 + 2] = t.z; c[i * 4 + 3] = t.w;
        }
        float a0 = 0.f, a1 = 0.f, a2 = 0.f, a3 = 0.f;
#pragma unroll
        for (int i = 0; i < 16; ++i) {
            const float4 w = *reinterpret_cast<const float4*>(&Wf2[(ks * 16 + i) * 128 + cg * 4]);
            a0 = fmaf(c[i], w.x, a0);
            a1 = fmaf(c[i], w.y, a1);
            a2 = fmaf(c[i], w.z, a2);
            a3 = fmaf(c[i], w.w, a3);
        }
        float4 o; o.x = a0; o.y = a1; o.z = a2; o.w = a3;
        *reinterpret_cast<float4*>(&part[ks][cg * 4]) = o;
    }
    __syncthreads();
    if (tid < 128) {
        float y = bf2[tid];
#pragma unroll
        for (int s = 0; s < 8; ++s) y += part[s][tid];
        out[gi * 128 + tid] = y;
    }
}

// ---------- host launch ----------
extern "C" void kernel_launch(void* const* d_in, const int* in_sizes, int n_in,
                              void* d_out, int out_size, void* d_ws, size_t ws_size,
                              hipStream_t stream) {
    const float* x    = (const float*)d_in[0];
    const int*   ei   = (const int*)d_in[1];
    const int*   batch= (const int*)d_in[2];
    const int*   cell = (const int*)d_in[3];
    const float* W1   = (const float*)d_in[4];
    const float* b1   = (const float*)d_in[5];
    const float* W2   = (const float*)d_in[6];
    const float* b2   = (const float*)d_in[7];
    const float* emb  = (const float*)d_in[8];
    const float* Wc   = (const float*)d_in[9];
    const float* bc   = (const float*)d_in[10];
    const float* lncw = (const float*)d_in[11];
    const float* lncb = (const float*)d_in[12];
    const float* Wf1  = (const float*)d_in[13];
    const float* bf1  = (const float*)d_in[14];
    const float* ln1w = (const float*)d_in[15];
    const float* ln1b = (const float*)d_in[16];
    const float* Wf2  = (const float*)d_in[17];
    const float* bf2  = (const float*)d_in[18];
    float* out = (float*)d_out;

    char* ws = (char*)d_ws;
    size_t off = 0;
    auto alloc = [&](size_t bytes) { char* p = ws + off; off = (off + bytes + 255) & ~size_t(255); return p; };
    float*          dinv        = (float*)alloc(N_NODES * 4);
    int*            rowbeg      = (int*)  alloc(N_NODES * 4);
    unsigned short* deg         = (unsigned short*)alloc(N_NODES * 2);
    unsigned short* colidx      = (unsigned short*)alloc((size_t)NBUCK * BCAP * 2);
    int*            bucketCursor= (int*)  alloc(NBUCK * 4);
    unsigned int*   recbuf      = (unsigned int*)alloc((size_t)NBUCK * BCAP * 4);
    unsigned short* wt1         = (unsigned short*)alloc(128 * 128 * 2);
    unsigned short* wt2         = (unsigned short*)alloc(128 * 128 * 2);
    unsigned short* hs          = (unsigned short*)alloc((size_t)N_NODES * 128 * 2);
    unsigned short* h1          = (unsigned short*)alloc((size_t)N_NODES * 128 * 2);
    unsigned short* h2b         = (unsigned short*)alloc((size_t)N_NODES * 128 * 2);

    const int nbEdge = (NEDGE + EPB - 1) / EPB;        // 196
    const int nbGemm = (N_NODES + 127) / 128;          // 391
    const int nbAgg  = (N_NODES + 3) / 4;              // 12500

    // weight cast + cursor init (one dispatch, precedes scatter)
    wcast_kernel<<<dim3(64, 2), 256, 0, stream>>>(W1, W2, wt1, wt2, bucketCursor);

    // CSR build (2 kernels)
    bucket_scatter_kernel<<<nbEdge, 256, 0, stream>>>(ei, bucketCursor, recbuf, NEDGE);
    bucket_csr_kernel<<<NBUCK, 256, 0, stream>>>(recbuf, bucketCursor, rowbeg, deg, dinv, colidx);

    // conv1
    gemm_mfma_kernel<true><<<nbGemm, 256, 0, stream>>>(x, wt1, dinv, hs, N_NODES);
    aggregate_kernel<<<nbAgg, 256, 0, stream>>>((const uint2*)hs, rowbeg, deg, colidx,
                                                dinv, b1, (uint2*)h1, N_NODES);
    // conv2
    gemm_mfma_kernel<false><<<nbGemm, 256, 0, stream>>>(h1, wt2, dinv, hs, N_NODES);
    aggregate_kernel<<<nbAgg, 256, 0, stream>>>((const uint2*)hs, rowbeg, deg, colidx,
                                                dinv, b2, (uint2*)h2b, N_NODES);
    // fused pool + tail
    tail_kernel<<<NGRAPH, 256, 0, stream>>>(h2b, batch, cell, emb, Wc, bc, lncw, lncb,
                                            Wf1, bf1, ln1w, ln1b, Wf2, bf2, out);
}